// Round 5
// baseline (539.888 us; speedup 1.0000x reference)
//
#include <hip/hip_runtime.h>
#include <math.h>
#include <stdint.h>

// ---------------------------------------------------------------------------
// GATv2 3-layer network on MI355X.
//   1) CSR build by dst (deg count -> 3-kernel scan -> scatter).
//   2) Weights pre-packed into MFMA B-fragment order as bf16 hi/lo pairs.
//   3) Per layer: ONE fused MFMA kernel computes xl=h@Wl+bl and xr=h@Wr+br,
//      both emitted fp16 (consumed only by attention), via split-bf16
//      (Xh*Wh + Xh*Wl + Xl*Wh ~ fp32 accuracy). Then attention: one wave per
//      dst node, 4x 16-lane edge groups, online softmax with defer-max,
//      packed-fp16 score math (v_pk_* + v_dot2_f32_f16), static 2-buffer
//      gather pipeline. Aggregation/output stay fp32.
//   4) Classifier GEMV per row.
// ---------------------------------------------------------------------------

typedef __attribute__((ext_vector_type(8))) short bf16x8;
typedef __attribute__((ext_vector_type(4))) float f32x4;
typedef __attribute__((ext_vector_type(8))) _Float16 half8;
typedef __attribute__((ext_vector_type(2))) _Float16 half2v;
typedef unsigned short ushort_t;

__device__ inline ushort_t bf16_rne(float f) {
  unsigned u = __float_as_uint(f);
  unsigned r = (u + 0x7FFFu + ((u >> 16) & 1u)) >> 16;
  return (ushort_t)r;
}
__device__ inline float bf16_to_f(ushort_t h) {
  return __uint_as_float(((unsigned)h) << 16);
}

__device__ inline float fdot2f(half2v a, half2v b, float c) {
#if __has_builtin(__builtin_amdgcn_fdot2)
  return __builtin_amdgcn_fdot2(a, b, c, false);
#else
  return c + (float)a[0] * (float)b[0] + (float)a[1] * (float)b[1];
#endif
}
__device__ inline half2v h2max(half2v a, half2v b) {
#if __has_builtin(__builtin_elementwise_max)
  return __builtin_elementwise_max(a, b);
#else
  half2v r;
  r[0] = a[0] > b[0] ? a[0] : b[0];
  r[1] = a[1] > b[1] ? a[1] : b[1];
  return r;
#endif
}

__global__ void zero_int_kernel(int* __restrict__ p, int n) {
  int i = blockIdx.x * blockDim.x + threadIdx.x;
  if (i < n) p[i] = 0;
}

__global__ void deg_count_kernel(const int* __restrict__ dst, int E, int n,
                                 int* __restrict__ deg) {
  int i = blockIdx.x * blockDim.x + threadIdx.x;
  int tot = E + n;
  if (i < tot) {
    int d = (i < E) ? dst[i] : (i - E);
    atomicAdd(&deg[d], 1);
  }
}

// 3-phase exclusive scan over deg[n], chunk=1024. nchunks must be <= 64.
__global__ __launch_bounds__(256) void block_sum_kernel(
    const int* __restrict__ deg, int n, int* __restrict__ partial) {
  __shared__ int sm[256];
  int base = blockIdx.x * 1024;
  int t = threadIdx.x;
  int sum = 0;
#pragma unroll
  for (int k = 0; k < 4; ++k) {
    int i = base + k * 256 + t;
    sum += (i < n) ? deg[i] : 0;
  }
  sm[t] = sum;
  __syncthreads();
  for (int off = 128; off > 0; off >>= 1) {
    if (t < off) sm[t] += sm[t + off];
    __syncthreads();
  }
  if (t == 0) partial[blockIdx.x] = sm[0];
}

__global__ void scan_partial_kernel(int* __restrict__ partial, int nchunks) {
  int lane = threadIdx.x;  // 64 threads
  int v = (lane < nchunks) ? partial[lane] : 0;
#pragma unroll
  for (int off = 1; off < 64; off <<= 1) {
    int u = __shfl_up(v, off, 64);
    if (lane >= off) v += u;
  }
  int ex = __shfl_up(v, 1, 64);
  if (lane == 0) ex = 0;
  if (lane < nchunks) partial[lane] = ex;
}

__global__ __launch_bounds__(1024) void block_scan_kernel(
    const int* __restrict__ deg, const int* __restrict__ partial,
    int* __restrict__ row_ptr, int* __restrict__ cursor, int n) {
  __shared__ int sm[1024];
  int i = blockIdx.x * 1024 + threadIdx.x;
  int v = (i < n) ? deg[i] : 0;
  sm[threadIdx.x] = v;
  __syncthreads();
  for (int off = 1; off < 1024; off <<= 1) {
    int t = (threadIdx.x >= off) ? sm[threadIdx.x - off] : 0;
    __syncthreads();
    sm[threadIdx.x] += t;
    __syncthreads();
  }
  int excl = partial[blockIdx.x] + sm[threadIdx.x] - v;
  if (i < n) {
    row_ptr[i] = excl;
    cursor[i] = excl;
  }
  if (i == n - 1) row_ptr[n] = excl + v;
}

__global__ void scatter_kernel(const int* __restrict__ src,
                               const int* __restrict__ dst, int E, int n,
                               int* __restrict__ cursor,
                               int* __restrict__ col_src) {
  int i = blockIdx.x * blockDim.x + threadIdx.x;
  int tot = E + n;
  if (i < tot) {
    int s = (i < E) ? src[i] : (i - E);
    int d = (i < E) ? dst[i] : (i - E);
    int slot = atomicAdd(&cursor[d], 1);
    col_src[slot] = s;
  }
}

// --------------------------- weight packing --------------------------------
// Fragment order for mfma_f32_16x16x32_bf16 B operand:
//   idx = ((ks*ntiles + t)*64 + lane)*8 + i -> W[ks*32+8*(lane>>4)+i][16t+(lane&15)]
struct PackArgs {
  const float* w[6];
  ushort_t* hi[6];
  ushort_t* lo[6];
  int ntiles[6];
  int N[6];
};

__global__ __launch_bounds__(256) void pack_w_kernel(PackArgs a) {
  int m = blockIdx.y;
  int ntiles = a.ntiles[m];
  int N = a.N[m];
  int tot = 4 * ntiles * 512;
  int idx = blockIdx.x * 256 + threadIdx.x;
  if (idx >= tot) return;
  int i = idx & 7;
  int lane = (idx >> 3) & 63;
  int t = (idx >> 9) % ntiles;
  int ks = idx / (512 * ntiles);
  int k = ks * 32 + (lane >> 4) * 8 + i;
  int c = t * 16 + (lane & 15);
  float f = a.w[m][k * N + c];
  ushort_t h = bf16_rne(f);
  a.hi[m][idx] = h;
  a.lo[m][idx] = bf16_rne(f - bf16_to_f(h));
}

// ----------------------- fused dual MFMA GEMM ------------------------------
// Yl (fp16) = X@Wl+Bl, Yr (fp16) = X@Wr+Br.  X: [M][128] fp32.
// Block: 256 thr = 4 waves; wave handles 16 rows x 128 cols (8 16x16 tiles).
// grid.y selects a 128-col panel (for N=256).
__global__ __launch_bounds__(256) void gemm_dual_mfma(
    const float* __restrict__ X, const ushort_t* __restrict__ wlhi,
    const ushort_t* __restrict__ wllo, const ushort_t* __restrict__ wrhi,
    const ushort_t* __restrict__ wrlo, const float* __restrict__ Bl,
    const float* __restrict__ Br, _Float16* __restrict__ Yl,
    _Float16* __restrict__ Yr, int M, int N, int ntot) {
  int lane = threadIdx.x & 63;
  int wv = threadIdx.x >> 6;
  int kg = lane >> 4;  // 0..3
  int li = lane & 15;
  int rbase = blockIdx.x * 64 + wv * 16;
  int colofs = blockIdx.y * 128;
  int tbase = colofs >> 4;
  int arow = rbase + li;
  int ar = (arow < M) ? arow : (M - 1);
  const float* xp = X + (size_t)ar * 128 + kg * 8;

  f32x4 accl[8], accr[8];
#pragma unroll
  for (int t = 0; t < 8; ++t) {
    accl[t] = (f32x4){0.f, 0.f, 0.f, 0.f};
    accr[t] = (f32x4){0.f, 0.f, 0.f, 0.f};
  }

#pragma unroll
  for (int ks = 0; ks < 4; ++ks) {
    float4 a0 = *reinterpret_cast<const float4*>(xp + ks * 32);
    float4 a1 = *reinterpret_cast<const float4*>(xp + ks * 32 + 4);
    float av[8] = {a0.x, a0.y, a0.z, a0.w, a1.x, a1.y, a1.z, a1.w};
    bf16x8 ah, al;
#pragma unroll
    for (int i = 0; i < 8; ++i) {
      ushort_t h = bf16_rne(av[i]);
      ah[i] = (short)h;
      al[i] = (short)bf16_rne(av[i] - bf16_to_f(h));
    }
    size_t fb = ((size_t)ks * ntot + tbase) * 512 + (size_t)lane * 8;
#pragma unroll
    for (int t = 0; t < 8; ++t) {
      size_t o = fb + (size_t)t * 512;
      bf16x8 blh = *reinterpret_cast<const bf16x8*>(wlhi + o);
      bf16x8 bll = *reinterpret_cast<const bf16x8*>(wllo + o);
      bf16x8 brh = *reinterpret_cast<const bf16x8*>(wrhi + o);
      bf16x8 brl = *reinterpret_cast<const bf16x8*>(wrlo + o);
      accl[t] = __builtin_amdgcn_mfma_f32_16x16x32_bf16(ah, blh, accl[t], 0, 0, 0);
      accl[t] = __builtin_amdgcn_mfma_f32_16x16x32_bf16(ah, bll, accl[t], 0, 0, 0);
      accl[t] = __builtin_amdgcn_mfma_f32_16x16x32_bf16(al, blh, accl[t], 0, 0, 0);
      accr[t] = __builtin_amdgcn_mfma_f32_16x16x32_bf16(ah, brh, accr[t], 0, 0, 0);
      accr[t] = __builtin_amdgcn_mfma_f32_16x16x32_bf16(ah, brl, accr[t], 0, 0, 0);
      accr[t] = __builtin_amdgcn_mfma_f32_16x16x32_bf16(al, brh, accr[t], 0, 0, 0);
    }
  }
  // D layout: row = 4*(lane>>4)+reg, col = 16t + (lane&15)
  int srow = rbase + kg * 4;
#pragma unroll
  for (int t = 0; t < 8; ++t) {
    int col = colofs + t * 16 + li;
    float bl = Bl[col];
    float br = Br[col];
#pragma unroll
    for (int r = 0; r < 4; ++r) {
      int rr = srow + r;
      if (rr < M) {
        Yl[(size_t)rr * N + col] = (_Float16)(accl[t][r] + bl);
        Yr[(size_t)rr * N + col] = (_Float16)(accr[t][r] + br);
      }
    }
  }
}

// --------------------------- attention -------------------------------------
// One wave per dst node; 4x 16-lane groups, each with its own online-softmax
// (defer-max, THR=8) over a strided slice of the edge list. fp16 payload,
// packed score math, static A/B gather pipeline (2 gathers in flight).
#define NEG_BIG (-1e30f)
template <int DOUT, bool RELU>
__global__ __launch_bounds__(256) void attn_kernel(
    const _Float16* __restrict__ xl, const _Float16* __restrict__ xr,
    const float* __restrict__ att, const float* __restrict__ bias,
    const int* __restrict__ row_ptr, const int* __restrict__ col_src,
    float* __restrict__ out, int M) {
  constexpr int NQ8 = DOUT / 128;  // half8 loads per lane per edge
  constexpr int NE = DOUT / 16;    // elements per lane (8 or 16)
  constexpr int NP = NE / 2;       // half2 pairs (4 or 8)
  int wid = (int)((blockIdx.x * blockDim.x + threadIdx.x) >> 6);
  int lane = threadIdx.x & 63;
  int grp = lane >> 4;
  int sl = lane & 15;
  if (wid >= M) return;

  // xr row (fp16) and att (as half2 pairs), per-lane columns q*128 + sl*8 + u
  half8 xr8[NQ8];
  const half8* xrp =
      reinterpret_cast<const half8*>(xr) + (size_t)wid * (DOUT / 8) + sl;
#pragma unroll
  for (int q = 0; q < NQ8; ++q) xr8[q] = xrp[q * 16];
  half2v att2[NP];
#pragma unroll
  for (int q = 0; q < NQ8; ++q) {
#pragma unroll
    for (int t = 0; t < 4; ++t) {
      int c = q * 128 + sl * 8 + t * 2;
      half2v a2;
      a2[0] = (_Float16)att[c];
      a2[1] = (_Float16)att[c + 1];
      att2[q * 4 + t] = a2;
    }
  }

  float acc[NE];
#pragma unroll
  for (int i = 0; i < NE; ++i) acc[i] = 0.f;
  float m = NEG_BIG, s = 0.f;
  int e0 = row_ptr[wid], e1 = row_ptr[wid + 1];
  int j = e0 + grp;  // this group's edge stream: j, j+4, j+8, ...

  const half8* base = reinterpret_cast<const half8*>(xl);
  half8 A[NQ8], B[NQ8];
  {
    int iA = (j < e1) ? col_src[j] : 0;
    int iB = (j + 4 < e1) ? col_src[j + 4] : 0;
#pragma unroll
    for (int q = 0; q < NQ8; ++q) A[q] = base[(size_t)iA * (DOUT / 8) + sl + q * 16];
#pragma unroll
    for (int q = 0; q < NQ8; ++q) B[q] = base[(size_t)iB * (DOUT / 8) + sl + q * 16];
  }

  auto process = [&](half8(&X)[NQ8], int nextIdx) {
    // packed leaky_relu(xl+xr) pairs
    half2v lk[NP];
    _Float16 c02 = (_Float16)0.2f;
    half2v v02;
    v02[0] = c02;
    v02[1] = c02;
#pragma unroll
    for (int q = 0; q < NQ8; ++q) {
      const half2v* xp = reinterpret_cast<const half2v*>(&X[q]);
      const half2v* rp = reinterpret_cast<const half2v*>(&xr8[q]);
#pragma unroll
      for (int t = 0; t < 4; ++t) {
        half2v tt = xp[t] + rp[t];
        lk[q * 4 + t] = h2max(tt, tt * v02);
      }
    }
    // fp32 copy for aggregation; X is then dead -> reissue gather into X
    float xf[NE];
#pragma unroll
    for (int q = 0; q < NQ8; ++q)
#pragma unroll
      for (int u = 0; u < 8; ++u) xf[q * 8 + u] = (float)X[q][u];
#pragma unroll
    for (int q = 0; q < NQ8; ++q)
      X[q] = base[(size_t)nextIdx * (DOUT / 8) + sl + q * 16];
    // score: fp32-accumulated fp16 dot
    float p = 0.f;
#pragma unroll
    for (int h = 0; h < NP; ++h) p = fdot2f(lk[h], att2[h], p);
#pragma unroll
    for (int off = 1; off < 16; off <<= 1) p += __shfl_xor(p, off, 64);
    if (p > m + 8.0f) {  // rare: new reference max
      float sc = __expf(m - p);
      s = s * sc + 1.f;
#pragma unroll
      for (int i = 0; i < NE; ++i) acc[i] = fmaf(acc[i], sc, xf[i]);
      m = p;
    } else {  // common: no rescale
      float pe = __expf(p - m);
      s += pe;
#pragma unroll
      for (int i = 0; i < NE; ++i) acc[i] = fmaf(pe, xf[i], acc[i]);
    }
  };

  while (j < e1) {
    int i2 = (j + 8 < e1) ? col_src[j + 8] : 0;
    process(A, i2);
    j += 4;
    if (j >= e1) break;
    i2 = (j + 8 < e1) ? col_src[j + 8] : 0;
    process(B, i2);
    j += 4;
  }

  // merge (m, s) across the 4 groups (m is each group's reference max)
  float mg = m;
  float mm = m, ss = s;
#pragma unroll
  for (int off = 16; off < 64; off <<= 1) {
    float mo = __shfl_xor(mm, off, 64);
    float so = __shfl_xor(ss, off, 64);
    float nm = fmaxf(mm, mo);
    ss = ss * __expf(mm - nm) + so * __expf(mo - nm);
    mm = nm;
  }
  float scale = __expf(mg - mm) / ss;  // ss > 0 (deg >= 1 via self-loop)
#pragma unroll
  for (int i = 0; i < NE; ++i) {
    float v = acc[i] * scale;
#pragma unroll
    for (int off = 16; off < 64; off <<= 1) v += __shfl_xor(v, off, 64);
    acc[i] = v;
  }
  // write: each group stores one float4 slice of the row
  if (NQ8 == 1) {
    if (grp < 2) {
      int c = sl * 8 + grp * 4;
      float4 b4 = *reinterpret_cast<const float4*>(bias + c);
      float4 o;
      o.x = acc[grp * 4 + 0] + b4.x;
      o.y = acc[grp * 4 + 1] + b4.y;
      o.z = acc[grp * 4 + 2] + b4.z;
      o.w = acc[grp * 4 + 3] + b4.w;
      if (RELU) {
        o.x = fmaxf(o.x, 0.f); o.y = fmaxf(o.y, 0.f);
        o.z = fmaxf(o.z, 0.f); o.w = fmaxf(o.w, 0.f);
      }
      *reinterpret_cast<float4*>(out + (size_t)wid * DOUT + c) = o;
    }
  } else {
    int q = grp >> 1, hf = grp & 1;
    int c = q * 128 + sl * 8 + hf * 4;
    float4 b4 = *reinterpret_cast<const float4*>(bias + c);
    float4 o;
    o.x = acc[q * 8 + hf * 4 + 0] + b4.x;
    o.y = acc[q * 8 + hf * 4 + 1] + b4.y;
    o.z = acc[q * 8 + hf * 4 + 2] + b4.z;
    o.w = acc[q * 8 + hf * 4 + 3] + b4.w;
    if (RELU) {
      o.x = fmaxf(o.x, 0.f); o.y = fmaxf(o.y, 0.f);
      o.z = fmaxf(o.z, 0.f); o.w = fmaxf(o.w, 0.f);
    }
    *reinterpret_cast<float4*>(out + (size_t)wid * DOUT + c) = o;
  }
}

// out[M][40] = H[M][256] @ WC[256][40] + BC.  One wave per row.
__global__ __launch_bounds__(256) void classifier_kernel(
    const float* __restrict__ H, const float* __restrict__ WC,
    const float* __restrict__ BC, float* __restrict__ out, int M) {
  __shared__ float rb[4][260];
  int wl = threadIdx.x >> 6;
  int lane = threadIdx.x & 63;
  int row = blockIdx.x * 4 + wl;
  bool valid = row < M;
  const float* hr = H + (size_t)(valid ? row : 0) * 256;
  float4 v = valid ? *reinterpret_cast<const float4*>(hr + lane * 4)
                   : make_float4(0.f, 0.f, 0.f, 0.f);
  *reinterpret_cast<float4*>(&rb[wl][lane * 4]) = v;
  __syncthreads();
  if (valid && lane < 40) {
    float acc = 0.f;
#pragma unroll 8
    for (int k = 0; k < 256; ++k) acc = fmaf(rb[wl][k], WC[k * 40 + lane], acc);
    out[(size_t)row * 40 + lane] = acc + BC[lane];
  }
}

extern "C" void kernel_launch(void* const* d_in, const int* in_sizes, int n_in,
                              void* d_out, int out_size, void* d_ws,
                              size_t ws_size, hipStream_t stream) {
  const float* x = (const float*)d_in[0];
  const int* ei = (const int*)d_in[1];
  const float* w1l = (const float*)d_in[2];
  const float* b1l = (const float*)d_in[3];
  const float* w1r = (const float*)d_in[4];
  const float* b1r = (const float*)d_in[5];
  const float* a1 = (const float*)d_in[6];
  const float* o1 = (const float*)d_in[7];
  const float* w2l = (const float*)d_in[8];
  const float* b2l = (const float*)d_in[9];
  const float* w2r = (const float*)d_in[10];
  const float* b2r = (const float*)d_in[11];
  const float* a2 = (const float*)d_in[12];
  const float* o2 = (const float*)d_in[13];
  const float* w3l = (const float*)d_in[14];
  const float* b3l = (const float*)d_in[15];
  const float* w3r = (const float*)d_in[16];
  const float* b3r = (const float*)d_in[17];
  const float* a3 = (const float*)d_in[18];
  const float* o3 = (const float*)d_in[19];
  const float* wc = (const float*)d_in[20];
  const float* bc = (const float*)d_in[21];
  float* out = (float*)d_out;

  const int n = in_sizes[0] / 128;  // 50000
  const int E = in_sizes[1] / 2;    // 800000
  const int tot = E + n;
  const int nchunks = (n + 1023) / 1024;  // <= 64 required

  // workspace layout
  char* p = (char*)d_ws;
  int* row_ptr = (int*)p; p += (size_t)(n + 1) * 4;
  int* deg = (int*)p;     p += (size_t)n * 4;
  int* cursor = (int*)p;  p += (size_t)n * 4;
  int* partial = (int*)p; p += (size_t)64 * 4;
  int* col_src = (int*)p; p += (size_t)tot * 4;
  p = (char*)(((uintptr_t)p + 255) & ~(uintptr_t)255);
  // packed weights: layers 1,2: 16384 elems per array; layer 3: 32768
  const size_t SZ12 = 16384, SZ3 = 32768;
  ushort_t* pk[12];
  for (int i = 0; i < 8; ++i) { pk[i] = (ushort_t*)p; p += SZ12 * 2; }
  for (int i = 8; i < 12; ++i) { pk[i] = (ushort_t*)p; p += SZ3 * 2; }
  p = (char*)(((uintptr_t)p + 255) & ~(uintptr_t)255);
  float* bufA = (float*)p;       p += (size_t)n * 256 * 4;  // attn out / next in
  _Float16* bufL = (_Float16*)p; p += (size_t)n * 256 * 2;  // xl (fp16)
  _Float16* bufR = (_Float16*)p;                            // xr (fp16)

  const int TPB = 256;

  // CSR build
  zero_int_kernel<<<(n + TPB - 1) / TPB, TPB, 0, stream>>>(deg, n);
  deg_count_kernel<<<(tot + TPB - 1) / TPB, TPB, 0, stream>>>(ei + E, E, n, deg);
  block_sum_kernel<<<nchunks, 256, 0, stream>>>(deg, n, partial);
  scan_partial_kernel<<<1, 64, 0, stream>>>(partial, nchunks);
  block_scan_kernel<<<nchunks, 1024, 0, stream>>>(deg, partial, row_ptr, cursor, n);
  scatter_kernel<<<(tot + TPB - 1) / TPB, TPB, 0, stream>>>(ei, ei + E, E, n,
                                                            cursor, col_src);

  // pack 6 weight matrices into MFMA B-fragment hi/lo arrays
  PackArgs pa;
  pa.w[0] = w1l; pa.w[1] = w1r; pa.w[2] = w2l; pa.w[3] = w2r;
  pa.w[4] = w3l; pa.w[5] = w3r;
  pa.hi[0] = pk[0]; pa.lo[0] = pk[1];
  pa.hi[1] = pk[2]; pa.lo[1] = pk[3];
  pa.hi[2] = pk[4]; pa.lo[2] = pk[5];
  pa.hi[3] = pk[6]; pa.lo[3] = pk[7];
  pa.hi[4] = pk[8]; pa.lo[4] = pk[9];
  pa.hi[5] = pk[10]; pa.lo[5] = pk[11];
  pa.ntiles[0] = pa.ntiles[1] = pa.ntiles[2] = pa.ntiles[3] = 8;
  pa.ntiles[4] = pa.ntiles[5] = 16;
  pa.N[0] = pa.N[1] = pa.N[2] = pa.N[3] = 128;
  pa.N[4] = pa.N[5] = 256;
  pack_w_kernel<<<dim3(128, 6), 256, 0, stream>>>(pa);

  const int gemmGrid = (n + 63) / 64;
  const int waveGrid = (n + 3) / 4;

  // Layer 1 (128 -> 128) + ReLU
  gemm_dual_mfma<<<dim3(gemmGrid, 1), TPB, 0, stream>>>(
      x, pk[0], pk[1], pk[2], pk[3], b1l, b1r, bufL, bufR, n, 128, 8);
  attn_kernel<128, true><<<waveGrid, TPB, 0, stream>>>(bufL, bufR, a1, o1,
                                                       row_ptr, col_src, bufA, n);
  // Layer 2 (128 -> 128) + ReLU
  gemm_dual_mfma<<<dim3(gemmGrid, 1), TPB, 0, stream>>>(
      bufA, pk[4], pk[5], pk[6], pk[7], b2l, b2r, bufL, bufR, n, 128, 8);
  attn_kernel<128, true><<<waveGrid, TPB, 0, stream>>>(bufL, bufR, a2, o2,
                                                       row_ptr, col_src, bufA, n);
  // Layer 3 (128 -> 256), no ReLU
  gemm_dual_mfma<<<dim3(gemmGrid, 2), TPB, 0, stream>>>(
      bufA, pk[8], pk[9], pk[10], pk[11], b3l, b3r, bufL, bufR, n, 256, 16);
  attn_kernel<256, false><<<waveGrid, TPB, 0, stream>>>(bufL, bufR, a3, o3,
                                                        row_ptr, col_src, bufA, n);
  // Classifier (256 -> 40)
  classifier_kernel<<<waveGrid, TPB, 0, stream>>>(bufA, wc, bc, out, n);
}

// Round 7
// 511.806 us; speedup vs baseline: 1.0549x; 1.0549x over previous
//
#include <hip/hip_runtime.h>
#include <math.h>
#include <stdint.h>

// ---------------------------------------------------------------------------
// GATv2 3-layer network on MI355X.
//   1) CSR build by dst (deg count -> 3-kernel scan -> scatter).
//   2) Weights pre-packed into MFMA B-fragment order as bf16 hi/lo pairs.
//   3) Per layer: ONE fused MFMA kernel computes xl=h@Wl+bl and xr=h@Wr+br,
//      both emitted fp16 (consumed only by attention), via split-bf16.
//      Then attention (ROUND-4 STRUCTURE, known-good): one wave per dst node,
//      4x 16-lane edge groups, 3-buffer half4 shift pipeline (2 gathers in
//      flight + index prefetch), packed-fp16 score (half2 add/mul/max + fdot2
//      fp32-acc), online softmax with defer-max (THR=8), fp32 aggregation.
//      NO lambdas / macros / bit_casts / address-taking in the hot loop
//      (r5: lambda ref param -> alloca -> LDS; r6: u32x4+bit_cast rewrite
//      miscompiled).
//   4) Classifier GEMV per row.
// ---------------------------------------------------------------------------

typedef __attribute__((ext_vector_type(8))) short bf16x8;
typedef __attribute__((ext_vector_type(4))) float f32x4;
typedef __attribute__((ext_vector_type(4))) _Float16 half4;
typedef __attribute__((ext_vector_type(2))) _Float16 half2v;
typedef unsigned short ushort_t;

__device__ inline ushort_t bf16_rne(float f) {
  unsigned u = __float_as_uint(f);
  unsigned r = (u + 0x7FFFu + ((u >> 16) & 1u)) >> 16;
  return (ushort_t)r;
}
__device__ inline float bf16_to_f(ushort_t h) {
  return __uint_as_float(((unsigned)h) << 16);
}

__device__ inline float fdot2f(half2v a, half2v b, float c) {
#if __has_builtin(__builtin_amdgcn_fdot2)
  return __builtin_amdgcn_fdot2(a, b, c, false);
#else
  return c + (float)a[0] * (float)b[0] + (float)a[1] * (float)b[1];
#endif
}
__device__ inline half2v h2max(half2v a, half2v b) {
#if __has_builtin(__builtin_elementwise_max)
  return __builtin_elementwise_max(a, b);
#else
  half2v r;
  r[0] = a[0] > b[0] ? a[0] : b[0];
  r[1] = a[1] > b[1] ? a[1] : b[1];
  return r;
#endif
}

__global__ void zero_int_kernel(int* __restrict__ p, int n) {
  int i = blockIdx.x * blockDim.x + threadIdx.x;
  if (i < n) p[i] = 0;
}

__global__ void deg_count_kernel(const int* __restrict__ dst, int E, int n,
                                 int* __restrict__ deg) {
  int i = blockIdx.x * blockDim.x + threadIdx.x;
  int tot = E + n;
  if (i < tot) {
    int d = (i < E) ? dst[i] : (i - E);
    atomicAdd(&deg[d], 1);
  }
}

// 3-phase exclusive scan over deg[n], chunk=1024. nchunks must be <= 64.
__global__ __launch_bounds__(256) void block_sum_kernel(
    const int* __restrict__ deg, int n, int* __restrict__ partial) {
  __shared__ int sm[256];
  int base = blockIdx.x * 1024;
  int t = threadIdx.x;
  int sum = 0;
#pragma unroll
  for (int k = 0; k < 4; ++k) {
    int i = base + k * 256 + t;
    sum += (i < n) ? deg[i] : 0;
  }
  sm[t] = sum;
  __syncthreads();
  for (int off = 128; off > 0; off >>= 1) {
    if (t < off) sm[t] += sm[t + off];
    __syncthreads();
  }
  if (t == 0) partial[blockIdx.x] = sm[0];
}

__global__ void scan_partial_kernel(int* __restrict__ partial, int nchunks) {
  int lane = threadIdx.x;  // 64 threads
  int v = (lane < nchunks) ? partial[lane] : 0;
#pragma unroll
  for (int off = 1; off < 64; off <<= 1) {
    int u = __shfl_up(v, off, 64);
    if (lane >= off) v += u;
  }
  int ex = __shfl_up(v, 1, 64);
  if (lane == 0) ex = 0;
  if (lane < nchunks) partial[lane] = ex;
}

__global__ __launch_bounds__(1024) void block_scan_kernel(
    const int* __restrict__ deg, const int* __restrict__ partial,
    int* __restrict__ row_ptr, int* __restrict__ cursor, int n) {
  __shared__ int sm[1024];
  int i = blockIdx.x * 1024 + threadIdx.x;
  int v = (i < n) ? deg[i] : 0;
  sm[threadIdx.x] = v;
  __syncthreads();
  for (int off = 1; off < 1024; off <<= 1) {
    int t = (threadIdx.x >= off) ? sm[threadIdx.x - off] : 0;
    __syncthreads();
    sm[threadIdx.x] += t;
    __syncthreads();
  }
  int excl = partial[blockIdx.x] + sm[threadIdx.x] - v;
  if (i < n) {
    row_ptr[i] = excl;
    cursor[i] = excl;
  }
  if (i == n - 1) row_ptr[n] = excl + v;
}

__global__ void scatter_kernel(const int* __restrict__ src,
                               const int* __restrict__ dst, int E, int n,
                               int* __restrict__ cursor,
                               int* __restrict__ col_src) {
  int i = blockIdx.x * blockDim.x + threadIdx.x;
  int tot = E + n;
  if (i < tot) {
    int s = (i < E) ? src[i] : (i - E);
    int d = (i < E) ? dst[i] : (i - E);
    int slot = atomicAdd(&cursor[d], 1);
    col_src[slot] = s;
  }
}

// --------------------------- weight packing --------------------------------
// Fragment order for mfma_f32_16x16x32_bf16 B operand:
//   idx = ((ks*ntiles + t)*64 + lane)*8 + i -> W[ks*32+8*(lane>>4)+i][16t+(lane&15)]
struct PackArgs {
  const float* w[6];
  ushort_t* hi[6];
  ushort_t* lo[6];
  int ntiles[6];
  int N[6];
};

__global__ __launch_bounds__(256) void pack_w_kernel(PackArgs a) {
  int m = blockIdx.y;
  int ntiles = a.ntiles[m];
  int N = a.N[m];
  int tot = 4 * ntiles * 512;
  int idx = blockIdx.x * 256 + threadIdx.x;
  if (idx >= tot) return;
  int i = idx & 7;
  int lane = (idx >> 3) & 63;
  int t = (idx >> 9) % ntiles;
  int ks = idx / (512 * ntiles);
  int k = ks * 32 + (lane >> 4) * 8 + i;
  int c = t * 16 + (lane & 15);
  float f = a.w[m][k * N + c];
  ushort_t h = bf16_rne(f);
  a.hi[m][idx] = h;
  a.lo[m][idx] = bf16_rne(f - bf16_to_f(h));
}

// ----------------------- fused dual MFMA GEMM ------------------------------
// Yl (fp16) = X@Wl+Bl, Yr (fp16) = X@Wr+Br.  X: [M][128] fp32.
// Block: 256 thr = 4 waves; wave handles 16 rows x 128 cols (8 16x16 tiles).
// grid.y selects a 128-col panel (for N=256).
__global__ __launch_bounds__(256) void gemm_dual_mfma(
    const float* __restrict__ X, const ushort_t* __restrict__ wlhi,
    const ushort_t* __restrict__ wllo, const ushort_t* __restrict__ wrhi,
    const ushort_t* __restrict__ wrlo, const float* __restrict__ Bl,
    const float* __restrict__ Br, _Float16* __restrict__ Yl,
    _Float16* __restrict__ Yr, int M, int N, int ntot) {
  int lane = threadIdx.x & 63;
  int wv = threadIdx.x >> 6;
  int kg = lane >> 4;  // 0..3
  int li = lane & 15;
  int rbase = blockIdx.x * 64 + wv * 16;
  int colofs = blockIdx.y * 128;
  int tbase = colofs >> 4;
  int arow = rbase + li;
  int ar = (arow < M) ? arow : (M - 1);
  const float* xp = X + (size_t)ar * 128 + kg * 8;

  f32x4 accl[8], accr[8];
#pragma unroll
  for (int t = 0; t < 8; ++t) {
    accl[t] = (f32x4){0.f, 0.f, 0.f, 0.f};
    accr[t] = (f32x4){0.f, 0.f, 0.f, 0.f};
  }

#pragma unroll
  for (int ks = 0; ks < 4; ++ks) {
    float4 a0 = *reinterpret_cast<const float4*>(xp + ks * 32);
    float4 a1 = *reinterpret_cast<const float4*>(xp + ks * 32 + 4);
    float av[8] = {a0.x, a0.y, a0.z, a0.w, a1.x, a1.y, a1.z, a1.w};
    bf16x8 ah, al;
#pragma unroll
    for (int i = 0; i < 8; ++i) {
      ushort_t h = bf16_rne(av[i]);
      ah[i] = (short)h;
      al[i] = (short)bf16_rne(av[i] - bf16_to_f(h));
    }
    size_t fb = ((size_t)ks * ntot + tbase) * 512 + (size_t)lane * 8;
#pragma unroll
    for (int t = 0; t < 8; ++t) {
      size_t o = fb + (size_t)t * 512;
      bf16x8 blh = *reinterpret_cast<const bf16x8*>(wlhi + o);
      bf16x8 bll = *reinterpret_cast<const bf16x8*>(wllo + o);
      bf16x8 brh = *reinterpret_cast<const bf16x8*>(wrhi + o);
      bf16x8 brl = *reinterpret_cast<const bf16x8*>(wrlo + o);
      accl[t] = __builtin_amdgcn_mfma_f32_16x16x32_bf16(ah, blh, accl[t], 0, 0, 0);
      accl[t] = __builtin_amdgcn_mfma_f32_16x16x32_bf16(ah, bll, accl[t], 0, 0, 0);
      accl[t] = __builtin_amdgcn_mfma_f32_16x16x32_bf16(al, blh, accl[t], 0, 0, 0);
      accr[t] = __builtin_amdgcn_mfma_f32_16x16x32_bf16(ah, brh, accr[t], 0, 0, 0);
      accr[t] = __builtin_amdgcn_mfma_f32_16x16x32_bf16(ah, brl, accr[t], 0, 0, 0);
      accr[t] = __builtin_amdgcn_mfma_f32_16x16x32_bf16(al, brh, accr[t], 0, 0, 0);
    }
  }
  // D layout: row = 4*(lane>>4)+reg, col = 16t + (lane&15)
  int srow = rbase + kg * 4;
#pragma unroll
  for (int t = 0; t < 8; ++t) {
    int col = colofs + t * 16 + li;
    float bl = Bl[col];
    float br = Br[col];
#pragma unroll
    for (int r = 0; r < 4; ++r) {
      int rr = srow + r;
      if (rr < M) {
        Yl[(size_t)rr * N + col] = (_Float16)(accl[t][r] + bl);
        Yr[(size_t)rr * N + col] = (_Float16)(accr[t][r] + br);
      }
    }
  }
}

// --------------------------- attention -------------------------------------
// Round-4 structure: one wave per dst node; 4x 16-lane groups, each with its
// own online-softmax over a strided slice of the edge list; 3-buffer half4
// shift pipeline (2 gathers in flight + index prefetch). Packed fp16 score,
// defer-max (THR=8), fp32 aggregation.
#define NEG_BIG (-1e30f)
template <int DOUT, bool RELU>
__global__ __launch_bounds__(256) void attn_kernel(
    const _Float16* __restrict__ xl, const _Float16* __restrict__ xr,
    const float* __restrict__ att, const float* __restrict__ bias,
    const int* __restrict__ row_ptr, const int* __restrict__ col_src,
    float* __restrict__ out, int M) {
  constexpr int NQ = DOUT / 64;  // half4 chunks per lane per edge
  constexpr int NE = NQ * 4;     // fp32 acc elements per lane
  int wid = (int)((blockIdx.x * blockDim.x + threadIdx.x) >> 6);
  int lane = threadIdx.x & 63;
  int grp = lane >> 4;
  int sl = lane & 15;
  if (wid >= M) return;

  // per-lane columns: q*64 + sl*4 + [0,4)
  half2v xr2[NQ * 2], att2[NQ * 2];
  {
    const half4* xrp =
        reinterpret_cast<const half4*>(xr) + (size_t)wid * (DOUT / 4) + sl;
#pragma unroll
    for (int q = 0; q < NQ; ++q) {
      half4 r4 = xrp[q * 16];
      half2v lo, hi;
      lo[0] = r4[0]; lo[1] = r4[1];
      hi[0] = r4[2]; hi[1] = r4[3];
      xr2[q * 2] = lo;
      xr2[q * 2 + 1] = hi;
    }
#pragma unroll
    for (int q = 0; q < NQ; ++q) {
#pragma unroll
      for (int t = 0; t < 2; ++t) {
        int c = q * 64 + sl * 4 + t * 2;
        half2v a2;
        a2[0] = (_Float16)att[c];
        a2[1] = (_Float16)att[c + 1];
        att2[q * 2 + t] = a2;
      }
    }
  }
  half2v v02;
  v02[0] = (_Float16)0.2f;
  v02[1] = (_Float16)0.2f;

  float acc[NE];
#pragma unroll
  for (int i = 0; i < NE; ++i) acc[i] = 0.f;
  float m = NEG_BIG, s = 0.f;
  int e0 = row_ptr[wid], e1 = row_ptr[wid + 1];
  int j = e0 + grp;  // this group's edge stream: j, j+4, j+8, ...

  const half4* base = reinterpret_cast<const half4*>(xl);
  half4 xv[NQ], xn[NQ], x2[NQ];
  half4 hz;
  hz[0] = hz[1] = hz[2] = hz[3] = (_Float16)0.f;
#pragma unroll
  for (int q = 0; q < NQ; ++q) {
    xv[q] = hz;
    xn[q] = hz;
    x2[q] = hz;
  }
  if (j < e1) {
    const half4* rp = base + (size_t)col_src[j] * (DOUT / 4) + sl;
#pragma unroll
    for (int q = 0; q < NQ; ++q) xv[q] = rp[q * 16];
  }
  if (j + 4 < e1) {
    const half4* rp = base + (size_t)col_src[j + 4] * (DOUT / 4) + sl;
#pragma unroll
    for (int q = 0; q < NQ; ++q) xn[q] = rp[q * 16];
  }
  int i2 = (j + 8 < e1) ? col_src[j + 8] : 0;

  while (j < e1) {
    int i3 = (j + 12 < e1) ? col_src[j + 12] : 0;  // index prefetch
    if (j + 8 < e1) {  // issue gather for edge j+8 (2 in flight)
      const half4* rp = base + (size_t)i2 * (DOUT / 4) + sl;
#pragma unroll
      for (int q = 0; q < NQ; ++q) x2[q] = rp[q * 16];
    }
    // packed fp16 score + fp32 copy for aggregation
    float p = 0.f;
    float xf[NE];
#pragma unroll
    for (int q = 0; q < NQ; ++q) {
#pragma unroll
      for (int t = 0; t < 2; ++t) {
        half2v xa;
        xa[0] = xv[q][2 * t];
        xa[1] = xv[q][2 * t + 1];
        half2v tt = xa + xr2[q * 2 + t];
        tt = h2max(tt, tt * v02);  // leaky_relu 0.2
        p = fdot2f(tt, att2[q * 2 + t], p);
        xf[q * 4 + 2 * t] = (float)xa[0];
        xf[q * 4 + 2 * t + 1] = (float)xa[1];
      }
    }
#pragma unroll
    for (int off = 1; off < 16; off <<= 1) p += __shfl_xor(p, off, 64);
    if (p > m + 8.0f) {  // rare: move reference max
      float sc = __expf(m - p);
      s = s * sc + 1.f;
#pragma unroll
      for (int i = 0; i < NE; ++i) acc[i] = fmaf(acc[i], sc, xf[i]);
      m = p;
    } else {  // common: no rescale, p - m <= 8 so pe <= e^8
      float pe = __expf(p - m);
      s += pe;
#pragma unroll
      for (int i = 0; i < NE; ++i) acc[i] = fmaf(pe, xf[i], acc[i]);
    }
#pragma unroll
    for (int q = 0; q < NQ; ++q) {
      xv[q] = xn[q];
      xn[q] = x2[q];
    }
    i2 = i3;
    j += 4;
  }
  // merge (m, s) across the 4 groups (m is each group's reference point)
  float mg = m;
  float mm = m, ss = s;
#pragma unroll
  for (int off = 16; off < 64; off <<= 1) {
    float mo = __shfl_xor(mm, off, 64);
    float so = __shfl_xor(ss, off, 64);
    float nm = fmaxf(mm, mo);
    ss = ss * __expf(mm - nm) + so * __expf(mo - nm);
    mm = nm;
  }
  float scale = __expf(mg - mm) / ss;  // ss > 0 (deg >= 1 via self-loop)
#pragma unroll
  for (int i = 0; i < NE; ++i) {
    float v = acc[i] * scale;
#pragma unroll
    for (int off = 16; off < 64; off <<= 1) v += __shfl_xor(v, off, 64);
    acc[i] = v;
  }
  // chunk q written by group (q & 3)
#pragma unroll
  for (int q = 0; q < NQ; ++q) {
    if (grp == (q & 3)) {
      int c = q * 64 + sl * 4;
      float4 b4 = *reinterpret_cast<const float4*>(bias + c);
      float4 o;
      o.x = acc[q * 4 + 0] + b4.x;
      o.y = acc[q * 4 + 1] + b4.y;
      o.z = acc[q * 4 + 2] + b4.z;
      o.w = acc[q * 4 + 3] + b4.w;
      if (RELU) {
        o.x = fmaxf(o.x, 0.f); o.y = fmaxf(o.y, 0.f);
        o.z = fmaxf(o.z, 0.f); o.w = fmaxf(o.w, 0.f);
      }
      *reinterpret_cast<float4*>(out + (size_t)wid * DOUT + c) = o;
    }
  }
}

// out[M][40] = H[M][256] @ WC[256][40] + BC.  One wave per row.
__global__ __launch_bounds__(256) void classifier_kernel(
    const float* __restrict__ H, const float* __restrict__ WC,
    const float* __restrict__ BC, float* __restrict__ out, int M) {
  __shared__ float rb[4][260];
  int wl = threadIdx.x >> 6;
  int lane = threadIdx.x & 63;
  int row = blockIdx.x * 4 + wl;
  bool valid = row < M;
  const float* hr = H + (size_t)(valid ? row : 0) * 256;
  float4 v = valid ? *reinterpret_cast<const float4*>(hr + lane * 4)
                   : make_float4(0.f, 0.f, 0.f, 0.f);
  *reinterpret_cast<float4*>(&rb[wl][lane * 4]) = v;
  __syncthreads();
  if (valid && lane < 40) {
    float acc = 0.f;
#pragma unroll 8
    for (int k = 0; k < 256; ++k) acc = fmaf(rb[wl][k], WC[k * 40 + lane], acc);
    out[(size_t)row * 40 + lane] = acc + BC[lane];
  }
}

extern "C" void kernel_launch(void* const* d_in, const int* in_sizes, int n_in,
                              void* d_out, int out_size, void* d_ws,
                              size_t ws_size, hipStream_t stream) {
  const float* x = (const float*)d_in[0];
  const int* ei = (const int*)d_in[1];
  const float* w1l = (const float*)d_in[2];
  const float* b1l = (const float*)d_in[3];
  const float* w1r = (const float*)d_in[4];
  const float* b1r = (const float*)d_in[5];
  const float* a1 = (const float*)d_in[6];
  const float* o1 = (const float*)d_in[7];
  const float* w2l = (const float*)d_in[8];
  const float* b2l = (const float*)d_in[9];
  const float* w2r = (const float*)d_in[10];
  const float* b2r = (const float*)d_in[11];
  const float* a2 = (const float*)d_in[12];
  const float* o2 = (const float*)d_in[13];
  const float* w3l = (const float*)d_in[14];
  const float* b3l = (const float*)d_in[15];
  const float* w3r = (const float*)d_in[16];
  const float* b3r = (const float*)d_in[17];
  const float* a3 = (const float*)d_in[18];
  const float* o3 = (const float*)d_in[19];
  const float* wc = (const float*)d_in[20];
  const float* bc = (const float*)d_in[21];
  float* out = (float*)d_out;

  const int n = in_sizes[0] / 128;  // 50000
  const int E = in_sizes[1] / 2;    // 800000
  const int tot = E + n;
  const int nchunks = (n + 1023) / 1024;  // <= 64 required

  // workspace layout
  char* p = (char*)d_ws;
  int* row_ptr = (int*)p; p += (size_t)(n + 1) * 4;
  int* deg = (int*)p;     p += (size_t)n * 4;
  int* cursor = (int*)p;  p += (size_t)n * 4;
  int* partial = (int*)p; p += (size_t)64 * 4;
  int* col_src = (int*)p; p += (size_t)tot * 4;
  p = (char*)(((uintptr_t)p + 255) & ~(uintptr_t)255);
  // packed weights: layers 1,2: 16384 elems per array; layer 3: 32768
  const size_t SZ12 = 16384, SZ3 = 32768;
  ushort_t* pk[12];
  for (int i = 0; i < 8; ++i) { pk[i] = (ushort_t*)p; p += SZ12 * 2; }
  for (int i = 8; i < 12; ++i) { pk[i] = (ushort_t*)p; p += SZ3 * 2; }
  p = (char*)(((uintptr_t)p + 255) & ~(uintptr_t)255);
  float* bufA = (float*)p;       p += (size_t)n * 256 * 4;  // attn out / next in
  _Float16* bufL = (_Float16*)p; p += (size_t)n * 256 * 2;  // xl (fp16)
  _Float16* bufR = (_Float16*)p;                            // xr (fp16)

  const int TPB = 256;

  // CSR build
  zero_int_kernel<<<(n + TPB - 1) / TPB, TPB, 0, stream>>>(deg, n);
  deg_count_kernel<<<(tot + TPB - 1) / TPB, TPB, 0, stream>>>(ei + E, E, n, deg);
  block_sum_kernel<<<nchunks, 256, 0, stream>>>(deg, n, partial);
  scan_partial_kernel<<<1, 64, 0, stream>>>(partial, nchunks);
  block_scan_kernel<<<nchunks, 1024, 0, stream>>>(deg, partial, row_ptr, cursor, n);
  scatter_kernel<<<(tot + TPB - 1) / TPB, TPB, 0, stream>>>(ei, ei + E, E, n,
                                                            cursor, col_src);

  // pack 6 weight matrices into MFMA B-fragment hi/lo arrays
  PackArgs pa;
  pa.w[0] = w1l; pa.w[1] = w1r; pa.w[2] = w2l; pa.w[3] = w2r;
  pa.w[4] = w3l; pa.w[5] = w3r;
  pa.hi[0] = pk[0]; pa.lo[0] = pk[1];
  pa.hi[1] = pk[2]; pa.lo[1] = pk[3];
  pa.hi[2] = pk[4]; pa.lo[2] = pk[5];
  pa.hi[3] = pk[6]; pa.lo[3] = pk[7];
  pa.hi[4] = pk[8]; pa.lo[4] = pk[9];
  pa.hi[5] = pk[10]; pa.lo[5] = pk[11];
  pa.ntiles[0] = pa.ntiles[1] = pa.ntiles[2] = pa.ntiles[3] = 8;
  pa.ntiles[4] = pa.ntiles[5] = 16;
  pa.N[0] = pa.N[1] = pa.N[2] = pa.N[3] = 128;
  pa.N[4] = pa.N[5] = 256;
  pack_w_kernel<<<dim3(128, 6), 256, 0, stream>>>(pa);

  const int gemmGrid = (n + 63) / 64;
  const int waveGrid = (n + 3) / 4;

  // Layer 1 (128 -> 128) + ReLU
  gemm_dual_mfma<<<dim3(gemmGrid, 1), TPB, 0, stream>>>(
      x, pk[0], pk[1], pk[2], pk[3], b1l, b1r, bufL, bufR, n, 128, 8);
  attn_kernel<128, true><<<waveGrid, TPB, 0, stream>>>(bufL, bufR, a1, o1,
                                                       row_ptr, col_src, bufA, n);
  // Layer 2 (128 -> 128) + ReLU
  gemm_dual_mfma<<<dim3(gemmGrid, 1), TPB, 0, stream>>>(
      bufA, pk[4], pk[5], pk[6], pk[7], b2l, b2r, bufL, bufR, n, 128, 8);
  attn_kernel<128, true><<<waveGrid, TPB, 0, stream>>>(bufL, bufR, a2, o2,
                                                       row_ptr, col_src, bufA, n);
  // Layer 3 (128 -> 256), no ReLU
  gemm_dual_mfma<<<dim3(gemmGrid, 2), TPB, 0, stream>>>(
      bufA, pk[8], pk[9], pk[10], pk[11], b3l, b3r, bufL, bufR, n, 256, 16);
  attn_kernel<256, false><<<waveGrid, TPB, 0, stream>>>(bufL, bufR, a3, o3,
                                                        row_ptr, col_src, bufA, n);
  // Classifier (256 -> 40)
  classifier_kernel<<<waveGrid, TPB, 0, stream>>>(bufA, wc, bc, out, n);
}

// Round 8
// 433.906 us; speedup vs baseline: 1.2443x; 1.1795x over previous
//
#include <hip/hip_runtime.h>
#include <math.h>
#include <stdint.h>

// ---------------------------------------------------------------------------
// GATv2 3-layer network on MI355X.
//   1) CSR build by dst (deg count -> 3-kernel scan -> scatter).
//   2) Weights (6 layer mats + classifier) pre-packed into MFMA B-fragment
//      order as bf16 hi/lo pairs (classifier zero-padded 40 -> 48 cols).
//   3) Per layer: ONE fused MFMA kernel computes xl=h@Wl+bl and xr=h@Wr+br,
//      both emitted fp16, via split-bf16 (Xh*Wh + Xh*Wl + Xl*Wh).
//      Then attention: one wave per dst node, 4x 16-lane edge groups,
//      3-buffer half4 shift pipeline, packed-fp16 score, defer-max.
//   4) Classifier via MFMA (was latency-bound GEMV at 103 us).
// ---------------------------------------------------------------------------

typedef __attribute__((ext_vector_type(8))) short bf16x8;
typedef __attribute__((ext_vector_type(4))) float f32x4;
typedef __attribute__((ext_vector_type(4))) _Float16 half4;
typedef __attribute__((ext_vector_type(2))) _Float16 half2v;
typedef unsigned short ushort_t;

__device__ inline ushort_t bf16_rne(float f) {
  unsigned u = __float_as_uint(f);
  unsigned r = (u + 0x7FFFu + ((u >> 16) & 1u)) >> 16;
  return (ushort_t)r;
}
__device__ inline float bf16_to_f(ushort_t h) {
  return __uint_as_float(((unsigned)h) << 16);
}

__device__ inline float fdot2f(half2v a, half2v b, float c) {
#if __has_builtin(__builtin_amdgcn_fdot2)
  return __builtin_amdgcn_fdot2(a, b, c, false);
#else
  return c + (float)a[0] * (float)b[0] + (float)a[1] * (float)b[1];
#endif
}
__device__ inline half2v h2max(half2v a, half2v b) {
#if __has_builtin(__builtin_elementwise_max)
  return __builtin_elementwise_max(a, b);
#else
  half2v r;
  r[0] = a[0] > b[0] ? a[0] : b[0];
  r[1] = a[1] > b[1] ? a[1] : b[1];
  return r;
#endif
}

__global__ void zero_int_kernel(int* __restrict__ p, int n) {
  int i = blockIdx.x * blockDim.x + threadIdx.x;
  if (i < n) p[i] = 0;
}

__global__ void deg_count_kernel(const int* __restrict__ dst, int E, int n,
                                 int* __restrict__ deg) {
  int i = blockIdx.x * blockDim.x + threadIdx.x;
  int tot = E + n;
  if (i < tot) {
    int d = (i < E) ? dst[i] : (i - E);
    atomicAdd(&deg[d], 1);
  }
}

// 3-phase exclusive scan over deg[n], chunk=1024. nchunks must be <= 64.
__global__ __launch_bounds__(256) void block_sum_kernel(
    const int* __restrict__ deg, int n, int* __restrict__ partial) {
  __shared__ int sm[256];
  int base = blockIdx.x * 1024;
  int t = threadIdx.x;
  int sum = 0;
#pragma unroll
  for (int k = 0; k < 4; ++k) {
    int i = base + k * 256 + t;
    sum += (i < n) ? deg[i] : 0;
  }
  sm[t] = sum;
  __syncthreads();
  for (int off = 128; off > 0; off >>= 1) {
    if (t < off) sm[t] += sm[t + off];
    __syncthreads();
  }
  if (t == 0) partial[blockIdx.x] = sm[0];
}

__global__ void scan_partial_kernel(int* __restrict__ partial, int nchunks) {
  int lane = threadIdx.x;  // 64 threads
  int v = (lane < nchunks) ? partial[lane] : 0;
#pragma unroll
  for (int off = 1; off < 64; off <<= 1) {
    int u = __shfl_up(v, off, 64);
    if (lane >= off) v += u;
  }
  int ex = __shfl_up(v, 1, 64);
  if (lane == 0) ex = 0;
  if (lane < nchunks) partial[lane] = ex;
}

__global__ __launch_bounds__(1024) void block_scan_kernel(
    const int* __restrict__ deg, const int* __restrict__ partial,
    int* __restrict__ row_ptr, int* __restrict__ cursor, int n) {
  __shared__ int sm[1024];
  int i = blockIdx.x * 1024 + threadIdx.x;
  int v = (i < n) ? deg[i] : 0;
  sm[threadIdx.x] = v;
  __syncthreads();
  for (int off = 1; off < 1024; off <<= 1) {
    int t = (threadIdx.x >= off) ? sm[threadIdx.x - off] : 0;
    __syncthreads();
    sm[threadIdx.x] += t;
    __syncthreads();
  }
  int excl = partial[blockIdx.x] + sm[threadIdx.x] - v;
  if (i < n) {
    row_ptr[i] = excl;
    cursor[i] = excl;
  }
  if (i == n - 1) row_ptr[n] = excl + v;
}

__global__ void scatter_kernel(const int* __restrict__ src,
                               const int* __restrict__ dst, int E, int n,
                               int* __restrict__ cursor,
                               int* __restrict__ col_src) {
  int i = blockIdx.x * blockDim.x + threadIdx.x;
  int tot = E + n;
  if (i < tot) {
    int s = (i < E) ? src[i] : (i - E);
    int d = (i < E) ? dst[i] : (i - E);
    int slot = atomicAdd(&cursor[d], 1);
    col_src[slot] = s;
  }
}

// --------------------------- weight packing --------------------------------
// Fragment order for mfma_f32_16x16x32_bf16 B operand:
//   idx = ((ks*ntiles + t)*64 + lane)*8 + i -> W[ks*32+8*(lane>>4)+i][16t+(lane&15)]
// Zero-pads columns c >= N (classifier: 40 cols padded to 3 tiles = 48).
struct PackArgs {
  const float* w[7];
  ushort_t* hi[7];
  ushort_t* lo[7];
  int ntiles[7];
  int kslices[7];
  int N[7];
};

__global__ __launch_bounds__(256) void pack_w_kernel(PackArgs a) {
  int m = blockIdx.y;
  int ntiles = a.ntiles[m];
  int N = a.N[m];
  int tot = a.kslices[m] * ntiles * 512;
  int idx = blockIdx.x * 256 + threadIdx.x;
  if (idx >= tot) return;
  int i = idx & 7;
  int lane = (idx >> 3) & 63;
  int t = (idx >> 9) % ntiles;
  int ks = idx / (512 * ntiles);
  int k = ks * 32 + (lane >> 4) * 8 + i;
  int c = t * 16 + (lane & 15);
  float f = (c < N) ? a.w[m][k * N + c] : 0.f;
  ushort_t h = bf16_rne(f);
  a.hi[m][idx] = h;
  a.lo[m][idx] = bf16_rne(f - bf16_to_f(h));
}

// ----------------------- fused dual MFMA GEMM ------------------------------
// Yl (fp16) = X@Wl+Bl, Yr (fp16) = X@Wr+Br.  X: [M][128] fp32.
// Block: 256 thr = 4 waves; wave handles 16 rows x 128 cols (8 16x16 tiles).
// grid.y selects a 128-col panel (for N=256).
__global__ __launch_bounds__(256) void gemm_dual_mfma(
    const float* __restrict__ X, const ushort_t* __restrict__ wlhi,
    const ushort_t* __restrict__ wllo, const ushort_t* __restrict__ wrhi,
    const ushort_t* __restrict__ wrlo, const float* __restrict__ Bl,
    const float* __restrict__ Br, _Float16* __restrict__ Yl,
    _Float16* __restrict__ Yr, int M, int N, int ntot) {
  int lane = threadIdx.x & 63;
  int wv = threadIdx.x >> 6;
  int kg = lane >> 4;  // 0..3
  int li = lane & 15;
  int rbase = blockIdx.x * 64 + wv * 16;
  int colofs = blockIdx.y * 128;
  int tbase = colofs >> 4;
  int arow = rbase + li;
  int ar = (arow < M) ? arow : (M - 1);
  const float* xp = X + (size_t)ar * 128 + kg * 8;

  f32x4 accl[8], accr[8];
#pragma unroll
  for (int t = 0; t < 8; ++t) {
    accl[t] = (f32x4){0.f, 0.f, 0.f, 0.f};
    accr[t] = (f32x4){0.f, 0.f, 0.f, 0.f};
  }

#pragma unroll
  for (int ks = 0; ks < 4; ++ks) {
    float4 a0 = *reinterpret_cast<const float4*>(xp + ks * 32);
    float4 a1 = *reinterpret_cast<const float4*>(xp + ks * 32 + 4);
    float av[8] = {a0.x, a0.y, a0.z, a0.w, a1.x, a1.y, a1.z, a1.w};
    bf16x8 ah, al;
#pragma unroll
    for (int i = 0; i < 8; ++i) {
      ushort_t h = bf16_rne(av[i]);
      ah[i] = (short)h;
      al[i] = (short)bf16_rne(av[i] - bf16_to_f(h));
    }
    size_t fb = ((size_t)ks * ntot + tbase) * 512 + (size_t)lane * 8;
#pragma unroll
    for (int t = 0; t < 8; ++t) {
      size_t o = fb + (size_t)t * 512;
      bf16x8 blh = *reinterpret_cast<const bf16x8*>(wlhi + o);
      bf16x8 bll = *reinterpret_cast<const bf16x8*>(wllo + o);
      bf16x8 brh = *reinterpret_cast<const bf16x8*>(wrhi + o);
      bf16x8 brl = *reinterpret_cast<const bf16x8*>(wrlo + o);
      accl[t] = __builtin_amdgcn_mfma_f32_16x16x32_bf16(ah, blh, accl[t], 0, 0, 0);
      accl[t] = __builtin_amdgcn_mfma_f32_16x16x32_bf16(ah, bll, accl[t], 0, 0, 0);
      accl[t] = __builtin_amdgcn_mfma_f32_16x16x32_bf16(al, blh, accl[t], 0, 0, 0);
      accr[t] = __builtin_amdgcn_mfma_f32_16x16x32_bf16(ah, brh, accr[t], 0, 0, 0);
      accr[t] = __builtin_amdgcn_mfma_f32_16x16x32_bf16(ah, brl, accr[t], 0, 0, 0);
      accr[t] = __builtin_amdgcn_mfma_f32_16x16x32_bf16(al, brh, accr[t], 0, 0, 0);
    }
  }
  // D layout: row = 4*(lane>>4)+reg, col = 16t + (lane&15)
  int srow = rbase + kg * 4;
#pragma unroll
  for (int t = 0; t < 8; ++t) {
    int col = colofs + t * 16 + li;
    float bl = Bl[col];
    float br = Br[col];
#pragma unroll
    for (int r = 0; r < 4; ++r) {
      int rr = srow + r;
      if (rr < M) {
        Yl[(size_t)rr * N + col] = (_Float16)(accl[t][r] + bl);
        Yr[(size_t)rr * N + col] = (_Float16)(accr[t][r] + br);
      }
    }
  }
}

// ----------------------- classifier via MFMA -------------------------------
// out[M][40] = H[M][256] @ WC[256][40] + BC.  WC packed to 3 tiles (48 cols,
// zero-padded), K=256 (8 k-slices). Same wave structure as gemm_dual_mfma.
__global__ __launch_bounds__(256) void classifier_mfma(
    const float* __restrict__ H, const ushort_t* __restrict__ wchi,
    const ushort_t* __restrict__ wclo, const float* __restrict__ BC,
    float* __restrict__ out, int M) {
  int lane = threadIdx.x & 63;
  int wv = threadIdx.x >> 6;
  int kg = lane >> 4;
  int li = lane & 15;
  int rbase = blockIdx.x * 64 + wv * 16;
  int arow = rbase + li;
  int ar = (arow < M) ? arow : (M - 1);
  const float* xp = H + (size_t)ar * 256 + kg * 8;

  f32x4 acc[3];
#pragma unroll
  for (int t = 0; t < 3; ++t) acc[t] = (f32x4){0.f, 0.f, 0.f, 0.f};

#pragma unroll
  for (int ks = 0; ks < 8; ++ks) {
    float4 a0 = *reinterpret_cast<const float4*>(xp + ks * 32);
    float4 a1 = *reinterpret_cast<const float4*>(xp + ks * 32 + 4);
    float av[8] = {a0.x, a0.y, a0.z, a0.w, a1.x, a1.y, a1.z, a1.w};
    bf16x8 ah, al;
#pragma unroll
    for (int i = 0; i < 8; ++i) {
      ushort_t h = bf16_rne(av[i]);
      ah[i] = (short)h;
      al[i] = (short)bf16_rne(av[i] - bf16_to_f(h));
    }
    size_t fb = ((size_t)ks * 3) * 512 + (size_t)lane * 8;
#pragma unroll
    for (int t = 0; t < 3; ++t) {
      size_t o = fb + (size_t)t * 512;
      bf16x8 bh = *reinterpret_cast<const bf16x8*>(wchi + o);
      bf16x8 bl = *reinterpret_cast<const bf16x8*>(wclo + o);
      acc[t] = __builtin_amdgcn_mfma_f32_16x16x32_bf16(ah, bh, acc[t], 0, 0, 0);
      acc[t] = __builtin_amdgcn_mfma_f32_16x16x32_bf16(ah, bl, acc[t], 0, 0, 0);
      acc[t] = __builtin_amdgcn_mfma_f32_16x16x32_bf16(al, bh, acc[t], 0, 0, 0);
    }
  }
  int srow = rbase + kg * 4;
#pragma unroll
  for (int t = 0; t < 3; ++t) {
    int col = t * 16 + li;
    if (col < 40) {
      float b = BC[col];
#pragma unroll
      for (int r = 0; r < 4; ++r) {
        int rr = srow + r;
        if (rr < M) out[(size_t)rr * 40 + col] = acc[t][r] + b;
      }
    }
  }
}

// --------------------------- attention -------------------------------------
// One wave per dst node; 4x 16-lane groups, each with its own online-softmax
// over a strided slice of the edge list; 3-buffer half4 shift pipeline
// (2 gathers in flight + index prefetch). Packed fp16 score, defer-max
// (THR=8), fp32 aggregation. NO lambdas/macros/bit_casts in the hot loop.
#define NEG_BIG (-1e30f)
template <int DOUT, bool RELU>
__global__ __launch_bounds__(256) void attn_kernel(
    const _Float16* __restrict__ xl, const _Float16* __restrict__ xr,
    const float* __restrict__ att, const float* __restrict__ bias,
    const int* __restrict__ row_ptr, const int* __restrict__ col_src,
    float* __restrict__ out, int M) {
  constexpr int NQ = DOUT / 64;  // half4 chunks per lane per edge
  constexpr int NE = NQ * 4;     // fp32 acc elements per lane
  int wid = (int)((blockIdx.x * blockDim.x + threadIdx.x) >> 6);
  int lane = threadIdx.x & 63;
  int grp = lane >> 4;
  int sl = lane & 15;
  if (wid >= M) return;

  // per-lane columns: q*64 + sl*4 + [0,4)
  half2v xr2[NQ * 2], att2[NQ * 2];
  {
    const half4* xrp =
        reinterpret_cast<const half4*>(xr) + (size_t)wid * (DOUT / 4) + sl;
#pragma unroll
    for (int q = 0; q < NQ; ++q) {
      half4 r4 = xrp[q * 16];
      half2v lo, hi;
      lo[0] = r4[0]; lo[1] = r4[1];
      hi[0] = r4[2]; hi[1] = r4[3];
      xr2[q * 2] = lo;
      xr2[q * 2 + 1] = hi;
    }
#pragma unroll
    for (int q = 0; q < NQ; ++q) {
#pragma unroll
      for (int t = 0; t < 2; ++t) {
        int c = q * 64 + sl * 4 + t * 2;
        half2v a2;
        a2[0] = (_Float16)att[c];
        a2[1] = (_Float16)att[c + 1];
        att2[q * 2 + t] = a2;
      }
    }
  }
  half2v v02;
  v02[0] = (_Float16)0.2f;
  v02[1] = (_Float16)0.2f;

  float acc[NE];
#pragma unroll
  for (int i = 0; i < NE; ++i) acc[i] = 0.f;
  float m = NEG_BIG, s = 0.f;
  int e0 = row_ptr[wid], e1 = row_ptr[wid + 1];
  int j = e0 + grp;  // this group's edge stream: j, j+4, j+8, ...

  const half4* base = reinterpret_cast<const half4*>(xl);
  half4 xv[NQ], xn[NQ], x2[NQ];
  half4 hz;
  hz[0] = hz[1] = hz[2] = hz[3] = (_Float16)0.f;
#pragma unroll
  for (int q = 0; q < NQ; ++q) {
    xv[q] = hz;
    xn[q] = hz;
    x2[q] = hz;
  }
  if (j < e1) {
    const half4* rp = base + (size_t)col_src[j] * (DOUT / 4) + sl;
#pragma unroll
    for (int q = 0; q < NQ; ++q) xv[q] = rp[q * 16];
  }
  if (j + 4 < e1) {
    const half4* rp = base + (size_t)col_src[j + 4] * (DOUT / 4) + sl;
#pragma unroll
    for (int q = 0; q < NQ; ++q) xn[q] = rp[q * 16];
  }
  int i2 = (j + 8 < e1) ? col_src[j + 8] : 0;

  while (j < e1) {
    int i3 = (j + 12 < e1) ? col_src[j + 12] : 0;  // index prefetch
    if (j + 8 < e1) {  // issue gather for edge j+8 (2 in flight)
      const half4* rp = base + (size_t)i2 * (DOUT / 4) + sl;
#pragma unroll
      for (int q = 0; q < NQ; ++q) x2[q] = rp[q * 16];
    }
    // packed fp16 score + fp32 copy for aggregation
    float p = 0.f;
    float xf[NE];
#pragma unroll
    for (int q = 0; q < NQ; ++q) {
#pragma unroll
      for (int t = 0; t < 2; ++t) {
        half2v xa;
        xa[0] = xv[q][2 * t];
        xa[1] = xv[q][2 * t + 1];
        half2v tt = xa + xr2[q * 2 + t];
        tt = h2max(tt, tt * v02);  // leaky_relu 0.2
        p = fdot2f(tt, att2[q * 2 + t], p);
        xf[q * 4 + 2 * t] = (float)xa[0];
        xf[q * 4 + 2 * t + 1] = (float)xa[1];
      }
    }
#pragma unroll
    for (int off = 1; off < 16; off <<= 1) p += __shfl_xor(p, off, 64);
    if (p > m + 8.0f) {  // rare: move reference max
      float sc = __expf(m - p);
      s = s * sc + 1.f;
#pragma unroll
      for (int i = 0; i < NE; ++i) acc[i] = fmaf(acc[i], sc, xf[i]);
      m = p;
    } else {  // common: no rescale, p - m <= 8 so pe <= e^8
      float pe = __expf(p - m);
      s += pe;
#pragma unroll
      for (int i = 0; i < NE; ++i) acc[i] = fmaf(pe, xf[i], acc[i]);
    }
#pragma unroll
    for (int q = 0; q < NQ; ++q) {
      xv[q] = xn[q];
      xn[q] = x2[q];
    }
    i2 = i3;
    j += 4;
  }
  // merge (m, s) across the 4 groups (m is each group's reference point)
  float mg = m;
  float mm = m, ss = s;
#pragma unroll
  for (int off = 16; off < 64; off <<= 1) {
    float mo = __shfl_xor(mm, off, 64);
    float so = __shfl_xor(ss, off, 64);
    float nm = fmaxf(mm, mo);
    ss = ss * __expf(mm - nm) + so * __expf(mo - nm);
    mm = nm;
  }
  float scale = __expf(mg - mm) / ss;  // ss > 0 (deg >= 1 via self-loop)
#pragma unroll
  for (int i = 0; i < NE; ++i) {
    float v = acc[i] * scale;
#pragma unroll
    for (int off = 16; off < 64; off <<= 1) v += __shfl_xor(v, off, 64);
    acc[i] = v;
  }
  // chunk q written by group (q & 3)
#pragma unroll
  for (int q = 0; q < NQ; ++q) {
    if (grp == (q & 3)) {
      int c = q * 64 + sl * 4;
      float4 b4 = *reinterpret_cast<const float4*>(bias + c);
      float4 o;
      o.x = acc[q * 4 + 0] + b4.x;
      o.y = acc[q * 4 + 1] + b4.y;
      o.z = acc[q * 4 + 2] + b4.z;
      o.w = acc[q * 4 + 3] + b4.w;
      if (RELU) {
        o.x = fmaxf(o.x, 0.f); o.y = fmaxf(o.y, 0.f);
        o.z = fmaxf(o.z, 0.f); o.w = fmaxf(o.w, 0.f);
      }
      *reinterpret_cast<float4*>(out + (size_t)wid * DOUT + c) = o;
    }
  }
}

extern "C" void kernel_launch(void* const* d_in, const int* in_sizes, int n_in,
                              void* d_out, int out_size, void* d_ws,
                              size_t ws_size, hipStream_t stream) {
  const float* x = (const float*)d_in[0];
  const int* ei = (const int*)d_in[1];
  const float* w1l = (const float*)d_in[2];
  const float* b1l = (const float*)d_in[3];
  const float* w1r = (const float*)d_in[4];
  const float* b1r = (const float*)d_in[5];
  const float* a1 = (const float*)d_in[6];
  const float* o1 = (const float*)d_in[7];
  const float* w2l = (const float*)d_in[8];
  const float* b2l = (const float*)d_in[9];
  const float* w2r = (const float*)d_in[10];
  const float* b2r = (const float*)d_in[11];
  const float* a2 = (const float*)d_in[12];
  const float* o2 = (const float*)d_in[13];
  const float* w3l = (const float*)d_in[14];
  const float* b3l = (const float*)d_in[15];
  const float* w3r = (const float*)d_in[16];
  const float* b3r = (const float*)d_in[17];
  const float* a3 = (const float*)d_in[18];
  const float* o3 = (const float*)d_in[19];
  const float* wc = (const float*)d_in[20];
  const float* bc = (const float*)d_in[21];
  float* out = (float*)d_out;

  const int n = in_sizes[0] / 128;  // 50000
  const int E = in_sizes[1] / 2;    // 800000
  const int tot = E + n;
  const int nchunks = (n + 1023) / 1024;  // <= 64 required

  // workspace layout
  char* p = (char*)d_ws;
  int* row_ptr = (int*)p; p += (size_t)(n + 1) * 4;
  int* deg = (int*)p;     p += (size_t)n * 4;
  int* cursor = (int*)p;  p += (size_t)n * 4;
  int* partial = (int*)p; p += (size_t)64 * 4;
  int* col_src = (int*)p; p += (size_t)tot * 4;
  p = (char*)(((uintptr_t)p + 255) & ~(uintptr_t)255);
  // packed weights: layers 1,2: 16384 elems; layer 3: 32768; wc: 12288
  const size_t SZ12 = 16384, SZ3 = 32768, SZC = 12288;
  ushort_t* pk[14];
  for (int i = 0; i < 8; ++i) { pk[i] = (ushort_t*)p; p += SZ12 * 2; }
  for (int i = 8; i < 12; ++i) { pk[i] = (ushort_t*)p; p += SZ3 * 2; }
  for (int i = 12; i < 14; ++i) { pk[i] = (ushort_t*)p; p += SZC * 2; }
  p = (char*)(((uintptr_t)p + 255) & ~(uintptr_t)255);
  float* bufA = (float*)p;       p += (size_t)n * 256 * 4;  // attn out / next in
  _Float16* bufL = (_Float16*)p; p += (size_t)n * 256 * 2;  // xl (fp16)
  _Float16* bufR = (_Float16*)p;                            // xr (fp16)

  const int TPB = 256;

  // CSR build
  zero_int_kernel<<<(n + TPB - 1) / TPB, TPB, 0, stream>>>(deg, n);
  deg_count_kernel<<<(tot + TPB - 1) / TPB, TPB, 0, stream>>>(ei + E, E, n, deg);
  block_sum_kernel<<<nchunks, 256, 0, stream>>>(deg, n, partial);
  scan_partial_kernel<<<1, 64, 0, stream>>>(partial, nchunks);
  block_scan_kernel<<<nchunks, 1024, 0, stream>>>(deg, partial, row_ptr, cursor, n);
  scatter_kernel<<<(tot + TPB - 1) / TPB, TPB, 0, stream>>>(ei, ei + E, E, n,
                                                            cursor, col_src);

  // pack 6 weight matrices + classifier into MFMA B-fragment hi/lo arrays
  PackArgs pa;
  pa.w[0] = w1l; pa.w[1] = w1r; pa.w[2] = w2l; pa.w[3] = w2r;
  pa.w[4] = w3l; pa.w[5] = w3r; pa.w[6] = wc;
  pa.hi[0] = pk[0]; pa.lo[0] = pk[1];
  pa.hi[1] = pk[2]; pa.lo[1] = pk[3];
  pa.hi[2] = pk[4]; pa.lo[2] = pk[5];
  pa.hi[3] = pk[6]; pa.lo[3] = pk[7];
  pa.hi[4] = pk[8]; pa.lo[4] = pk[9];
  pa.hi[5] = pk[10]; pa.lo[5] = pk[11];
  pa.hi[6] = pk[12]; pa.lo[6] = pk[13];
  pa.ntiles[0] = pa.ntiles[1] = pa.ntiles[2] = pa.ntiles[3] = 8;
  pa.ntiles[4] = pa.ntiles[5] = 16;
  pa.ntiles[6] = 3;
  pa.kslices[0] = pa.kslices[1] = pa.kslices[2] = pa.kslices[3] = 4;
  pa.kslices[4] = pa.kslices[5] = 4;
  pa.kslices[6] = 8;
  pa.N[0] = pa.N[1] = pa.N[2] = pa.N[3] = 128;
  pa.N[4] = pa.N[5] = 256;
  pa.N[6] = 40;
  pack_w_kernel<<<dim3(128, 7), 256, 0, stream>>>(pa);

  const int gemmGrid = (n + 63) / 64;
  const int waveGrid = (n + 3) / 4;

  // Layer 1 (128 -> 128) + ReLU
  gemm_dual_mfma<<<dim3(gemmGrid, 1), TPB, 0, stream>>>(
      x, pk[0], pk[1], pk[2], pk[3], b1l, b1r, bufL, bufR, n, 128, 8);
  attn_kernel<128, true><<<waveGrid, TPB, 0, stream>>>(bufL, bufR, a1, o1,
                                                       row_ptr, col_src, bufA, n);
  // Layer 2 (128 -> 128) + ReLU
  gemm_dual_mfma<<<dim3(gemmGrid, 1), TPB, 0, stream>>>(
      bufA, pk[4], pk[5], pk[6], pk[7], b2l, b2r, bufL, bufR, n, 128, 8);
  attn_kernel<128, true><<<waveGrid, TPB, 0, stream>>>(bufL, bufR, a2, o2,
                                                       row_ptr, col_src, bufA, n);
  // Layer 3 (128 -> 256), no ReLU
  gemm_dual_mfma<<<dim3(gemmGrid, 2), TPB, 0, stream>>>(
      bufA, pk[8], pk[9], pk[10], pk[11], b3l, b3r, bufL, bufR, n, 256, 16);
  attn_kernel<256, false><<<waveGrid, TPB, 0, stream>>>(bufL, bufR, a3, o3,
                                                        row_ptr, col_src, bufA, n);
  // Classifier (256 -> 40) via MFMA
  classifier_mfma<<<gemmGrid, TPB, 0, stream>>>(bufA, pk[12], pk[13], bc, out, n);
}

// Round 9
// 407.070 us; speedup vs baseline: 1.3263x; 1.0659x over previous
//
#include <hip/hip_runtime.h>
#include <math.h>
#include <stdint.h>

// ---------------------------------------------------------------------------
// GATv2 3-layer network on MI355X.
//   1) CSR build by dst (deg count -> 3-kernel scan -> scatter).
//   2) Weights (6 layer mats + classifier) pre-packed into MFMA B-fragment
//      order as bf16 hi/lo pairs (classifier zero-padded 40 -> 48 cols).
//   3) Per layer: ONE fused MFMA kernel computes xl=h@Wl+bl and xr=h@Wr+br,
//      both emitted fp16, via split-bf16 (Xh*Wh + Xh*Wl + Xl*Wh). Hidden
//      state h is fp16 end-to-end (attn output fp16; GEMM input templated).
//      Attention: one wave per dst node, 4x 16-lane edge groups, 3-buffer
//      UNROLLED rotation (no shift movs, 3 gathers in flight), packed-fp16
//      score, defer-max. The PROC3 macro body is textually the round-7-
//      verified code (half4 extracts only; no bit_cast/u32x4 — r6 lesson).
//   4) Classifier via MFMA (fp16 input).
// ---------------------------------------------------------------------------

typedef __attribute__((ext_vector_type(8))) short bf16x8;
typedef __attribute__((ext_vector_type(4))) float f32x4;
typedef __attribute__((ext_vector_type(4))) _Float16 half4;
typedef __attribute__((ext_vector_type(8))) _Float16 half8;
typedef __attribute__((ext_vector_type(2))) _Float16 half2v;
typedef unsigned short ushort_t;

__device__ inline ushort_t bf16_rne(float f) {
  unsigned u = __float_as_uint(f);
  unsigned r = (u + 0x7FFFu + ((u >> 16) & 1u)) >> 16;
  return (ushort_t)r;
}
__device__ inline float bf16_to_f(ushort_t h) {
  return __uint_as_float(((unsigned)h) << 16);
}

__device__ inline float fdot2f(half2v a, half2v b, float c) {
#if __has_builtin(__builtin_amdgcn_fdot2)
  return __builtin_amdgcn_fdot2(a, b, c, false);
#else
  return c + (float)a[0] * (float)b[0] + (float)a[1] * (float)b[1];
#endif
}
__device__ inline half2v h2max(half2v a, half2v b) {
#if __has_builtin(__builtin_elementwise_max)
  return __builtin_elementwise_max(a, b);
#else
  half2v r;
  r[0] = a[0] > b[0] ? a[0] : b[0];
  r[1] = a[1] > b[1] ? a[1] : b[1];
  return r;
#endif
}

__global__ void zero_int_kernel(int* __restrict__ p, int n) {
  int i = blockIdx.x * blockDim.x + threadIdx.x;
  if (i < n) p[i] = 0;
}

__global__ void deg_count_kernel(const int* __restrict__ dst, int E, int n,
                                 int* __restrict__ deg) {
  int i = blockIdx.x * blockDim.x + threadIdx.x;
  int tot = E + n;
  if (i < tot) {
    int d = (i < E) ? dst[i] : (i - E);
    atomicAdd(&deg[d], 1);
  }
}

// 3-phase exclusive scan over deg[n], chunk=1024. nchunks must be <= 64.
__global__ __launch_bounds__(256) void block_sum_kernel(
    const int* __restrict__ deg, int n, int* __restrict__ partial) {
  __shared__ int sm[256];
  int base = blockIdx.x * 1024;
  int t = threadIdx.x;
  int sum = 0;
#pragma unroll
  for (int k = 0; k < 4; ++k) {
    int i = base + k * 256 + t;
    sum += (i < n) ? deg[i] : 0;
  }
  sm[t] = sum;
  __syncthreads();
  for (int off = 128; off > 0; off >>= 1) {
    if (t < off) sm[t] += sm[t + off];
    __syncthreads();
  }
  if (t == 0) partial[blockIdx.x] = sm[0];
}

__global__ void scan_partial_kernel(int* __restrict__ partial, int nchunks) {
  int lane = threadIdx.x;  // 64 threads
  int v = (lane < nchunks) ? partial[lane] : 0;
#pragma unroll
  for (int off = 1; off < 64; off <<= 1) {
    int u = __shfl_up(v, off, 64);
    if (lane >= off) v += u;
  }
  int ex = __shfl_up(v, 1, 64);
  if (lane == 0) ex = 0;
  if (lane < nchunks) partial[lane] = ex;
}

__global__ __launch_bounds__(1024) void block_scan_kernel(
    const int* __restrict__ deg, const int* __restrict__ partial,
    int* __restrict__ row_ptr, int* __restrict__ cursor, int n) {
  __shared__ int sm[1024];
  int i = blockIdx.x * 1024 + threadIdx.x;
  int v = (i < n) ? deg[i] : 0;
  sm[threadIdx.x] = v;
  __syncthreads();
  for (int off = 1; off < 1024; off <<= 1) {
    int t = (threadIdx.x >= off) ? sm[threadIdx.x - off] : 0;
    __syncthreads();
    sm[threadIdx.x] += t;
    __syncthreads();
  }
  int excl = partial[blockIdx.x] + sm[threadIdx.x] - v;
  if (i < n) {
    row_ptr[i] = excl;
    cursor[i] = excl;
  }
  if (i == n - 1) row_ptr[n] = excl + v;
}

__global__ void scatter_kernel(const int* __restrict__ src,
                               const int* __restrict__ dst, int E, int n,
                               int* __restrict__ cursor,
                               int* __restrict__ col_src) {
  int i = blockIdx.x * blockDim.x + threadIdx.x;
  int tot = E + n;
  if (i < tot) {
    int s = (i < E) ? src[i] : (i - E);
    int d = (i < E) ? dst[i] : (i - E);
    int slot = atomicAdd(&cursor[d], 1);
    col_src[slot] = s;
  }
}

// --------------------------- weight packing --------------------------------
// Fragment order for mfma_f32_16x16x32_bf16 B operand:
//   idx = ((ks*ntiles + t)*64 + lane)*8 + i -> W[ks*32+8*(lane>>4)+i][16t+(lane&15)]
// Zero-pads columns c >= N (classifier: 40 cols padded to 3 tiles = 48).
struct PackArgs {
  const float* w[7];
  ushort_t* hi[7];
  ushort_t* lo[7];
  int ntiles[7];
  int kslices[7];
  int N[7];
};

__global__ __launch_bounds__(256) void pack_w_kernel(PackArgs a) {
  int m = blockIdx.y;
  int ntiles = a.ntiles[m];
  int N = a.N[m];
  int tot = a.kslices[m] * ntiles * 512;
  int idx = blockIdx.x * 256 + threadIdx.x;
  if (idx >= tot) return;
  int i = idx & 7;
  int lane = (idx >> 3) & 63;
  int t = (idx >> 9) % ntiles;
  int ks = idx / (512 * ntiles);
  int k = ks * 32 + (lane >> 4) * 8 + i;
  int c = t * 16 + (lane & 15);
  float f = (c < N) ? a.w[m][k * N + c] : 0.f;
  ushort_t h = bf16_rne(f);
  a.hi[m][idx] = h;
  a.lo[m][idx] = bf16_rne(f - bf16_to_f(h));
}

// ----------------------- fused dual MFMA GEMM ------------------------------
// Yl (fp16) = X@Wl+Bl, Yr (fp16) = X@Wr+Br.  X: [M][128] fp32 OR fp16.
// Block: 256 thr = 4 waves; wave handles 16 rows x 128 cols (8 16x16 tiles).
// grid.y selects a 128-col panel (for N=256).
template <typename TIN>
__global__ __launch_bounds__(256) void gemm_dual_mfma(
    const TIN* __restrict__ X, const ushort_t* __restrict__ wlhi,
    const ushort_t* __restrict__ wllo, const ushort_t* __restrict__ wrhi,
    const ushort_t* __restrict__ wrlo, const float* __restrict__ Bl,
    const float* __restrict__ Br, _Float16* __restrict__ Yl,
    _Float16* __restrict__ Yr, int M, int N, int ntot) {
  int lane = threadIdx.x & 63;
  int wv = threadIdx.x >> 6;
  int kg = lane >> 4;  // 0..3
  int li = lane & 15;
  int rbase = blockIdx.x * 64 + wv * 16;
  int colofs = blockIdx.y * 128;
  int tbase = colofs >> 4;
  int arow = rbase + li;
  int ar = (arow < M) ? arow : (M - 1);
  const TIN* xp = X + (size_t)ar * 128 + kg * 8;

  f32x4 accl[8], accr[8];
#pragma unroll
  for (int t = 0; t < 8; ++t) {
    accl[t] = (f32x4){0.f, 0.f, 0.f, 0.f};
    accr[t] = (f32x4){0.f, 0.f, 0.f, 0.f};
  }

#pragma unroll
  for (int ks = 0; ks < 4; ++ks) {
    float av[8];
    if constexpr (sizeof(TIN) == 4) {
      float4 a0 = *reinterpret_cast<const float4*>(xp + ks * 32);
      float4 a1 = *reinterpret_cast<const float4*>(xp + ks * 32 + 4);
      av[0] = a0.x; av[1] = a0.y; av[2] = a0.z; av[3] = a0.w;
      av[4] = a1.x; av[5] = a1.y; av[6] = a1.z; av[7] = a1.w;
    } else {
      half8 h8 = *reinterpret_cast<const half8*>(xp + ks * 32);
#pragma unroll
      for (int i = 0; i < 8; ++i) av[i] = (float)h8[i];
    }
    bf16x8 ah, al;
#pragma unroll
    for (int i = 0; i < 8; ++i) {
      ushort_t h = bf16_rne(av[i]);
      ah[i] = (short)h;
      al[i] = (short)bf16_rne(av[i] - bf16_to_f(h));
    }
    size_t fb = ((size_t)ks * ntot + tbase) * 512 + (size_t)lane * 8;
#pragma unroll
    for (int t = 0; t < 8; ++t) {
      size_t o = fb + (size_t)t * 512;
      bf16x8 blh = *reinterpret_cast<const bf16x8*>(wlhi + o);
      bf16x8 bll = *reinterpret_cast<const bf16x8*>(wllo + o);
      bf16x8 brh = *reinterpret_cast<const bf16x8*>(wrhi + o);
      bf16x8 brl = *reinterpret_cast<const bf16x8*>(wrlo + o);
      accl[t] = __builtin_amdgcn_mfma_f32_16x16x32_bf16(ah, blh, accl[t], 0, 0, 0);
      accl[t] = __builtin_amdgcn_mfma_f32_16x16x32_bf16(ah, bll, accl[t], 0, 0, 0);
      accl[t] = __builtin_amdgcn_mfma_f32_16x16x32_bf16(al, blh, accl[t], 0, 0, 0);
      accr[t] = __builtin_amdgcn_mfma_f32_16x16x32_bf16(ah, brh, accr[t], 0, 0, 0);
      accr[t] = __builtin_amdgcn_mfma_f32_16x16x32_bf16(ah, brl, accr[t], 0, 0, 0);
      accr[t] = __builtin_amdgcn_mfma_f32_16x16x32_bf16(al, brh, accr[t], 0, 0, 0);
    }
  }
  // D layout: row = 4*(lane>>4)+reg, col = 16t + (lane&15)
  int srow = rbase + kg * 4;
#pragma unroll
  for (int t = 0; t < 8; ++t) {
    int col = colofs + t * 16 + li;
    float bl = Bl[col];
    float br = Br[col];
#pragma unroll
    for (int r = 0; r < 4; ++r) {
      int rr = srow + r;
      if (rr < M) {
        Yl[(size_t)rr * N + col] = (_Float16)(accl[t][r] + bl);
        Yr[(size_t)rr * N + col] = (_Float16)(accr[t][r] + br);
      }
    }
  }
}

// ----------------------- classifier via MFMA -------------------------------
// out[M][40] = H[M][256] @ WC[256][40] + BC.  H fp16. WC packed to 3 tiles.
__global__ __launch_bounds__(256) void classifier_mfma(
    const _Float16* __restrict__ H, const ushort_t* __restrict__ wchi,
    const ushort_t* __restrict__ wclo, const float* __restrict__ BC,
    float* __restrict__ out, int M) {
  int lane = threadIdx.x & 63;
  int wv = threadIdx.x >> 6;
  int kg = lane >> 4;
  int li = lane & 15;
  int rbase = blockIdx.x * 64 + wv * 16;
  int arow = rbase + li;
  int ar = (arow < M) ? arow : (M - 1);
  const _Float16* xp = H + (size_t)ar * 256 + kg * 8;

  f32x4 acc[3];
#pragma unroll
  for (int t = 0; t < 3; ++t) acc[t] = (f32x4){0.f, 0.f, 0.f, 0.f};

#pragma unroll
  for (int ks = 0; ks < 8; ++ks) {
    half8 h8 = *reinterpret_cast<const half8*>(xp + ks * 32);
    bf16x8 ah, al;
#pragma unroll
    for (int i = 0; i < 8; ++i) {
      float f = (float)h8[i];
      ushort_t h = bf16_rne(f);
      ah[i] = (short)h;
      al[i] = (short)bf16_rne(f - bf16_to_f(h));
    }
    size_t fb = ((size_t)ks * 3) * 512 + (size_t)lane * 8;
#pragma unroll
    for (int t = 0; t < 3; ++t) {
      size_t o = fb + (size_t)t * 512;
      bf16x8 bh = *reinterpret_cast<const bf16x8*>(wchi + o);
      bf16x8 bl = *reinterpret_cast<const bf16x8*>(wclo + o);
      acc[t] = __builtin_amdgcn_mfma_f32_16x16x32_bf16(ah, bh, acc[t], 0, 0, 0);
      acc[t] = __builtin_amdgcn_mfma_f32_16x16x32_bf16(ah, bl, acc[t], 0, 0, 0);
      acc[t] = __builtin_amdgcn_mfma_f32_16x16x32_bf16(al, bh, acc[t], 0, 0, 0);
    }
  }
  int srow = rbase + kg * 4;
#pragma unroll
  for (int t = 0; t < 3; ++t) {
    int col = t * 16 + li;
    if (col < 40) {
      float b = BC[col];
#pragma unroll
      for (int r = 0; r < 4; ++r) {
        int rr = srow + r;
        if (rr < M) out[(size_t)rr * 40 + col] = acc[t][r] + b;
      }
    }
  }
}

// --------------------------- attention -------------------------------------
// One wave per dst node; 4x 16-lane groups, each with its own online-softmax
// over a strided slice of the edge list. 3-buffer UNROLLED rotation: PROC3(X)
// consumes buffer X (edge j) and reissues its gather for edge j+12. Body is
// textually the round-7-verified code. Packed fp16 score, defer-max (THR=8),
// fp32 aggregation, fp16 output.
#define NEG_BIG (-1e30f)

#define PROC3(X)                                                          \
  {                                                                       \
    int inx = (j + 12 < e1) ? col_src[j + 12] : 0;                        \
    float p = 0.f;                                                        \
    float xf[NE];                                                         \
    _Pragma("unroll") for (int q = 0; q < NQ; ++q) {                      \
      _Pragma("unroll") for (int t = 0; t < 2; ++t) {                     \
        half2v xa;                                                        \
        xa[0] = X[q][2 * t];                                              \
        xa[1] = X[q][2 * t + 1];                                          \
        half2v tt = xa + xr2[q * 2 + t];                                  \
        tt = h2max(tt, tt * v02);                                         \
        p = fdot2f(tt, att2[q * 2 + t], p);                               \
        xf[q * 4 + 2 * t] = (float)xa[0];                                 \
        xf[q * 4 + 2 * t + 1] = (float)xa[1];                             \
      }                                                                   \
    }                                                                     \
    {                                                                     \
      const half4* rp = base + (size_t)inx * (DOUT / 4) + sl;             \
      _Pragma("unroll") for (int q = 0; q < NQ; ++q) X[q] = rp[q * 16];   \
    }                                                                     \
    _Pragma("unroll") for (int off = 1; off < 16; off <<= 1)              \
        p += __shfl_xor(p, off, 64);                                      \
    if (p > m + 8.0f) {                                                   \
      float sc = __expf(m - p);                                           \
      s = s * sc + 1.f;                                                   \
      _Pragma("unroll") for (int i = 0; i < NE; ++i)                      \
          acc[i] = fmaf(acc[i], sc, xf[i]);                               \
      m = p;                                                              \
    } else {                                                              \
      float pe = __expf(p - m);                                           \
      s += pe;                                                            \
      _Pragma("unroll") for (int i = 0; i < NE; ++i)                      \
          acc[i] = fmaf(pe, xf[i], acc[i]);                               \
    }                                                                     \
  }

template <int DOUT, bool RELU>
__global__ __launch_bounds__(256) void attn_kernel(
    const _Float16* __restrict__ xl, const _Float16* __restrict__ xr,
    const float* __restrict__ att, const float* __restrict__ bias,
    const int* __restrict__ row_ptr, const int* __restrict__ col_src,
    _Float16* __restrict__ out, int M) {
  constexpr int NQ = DOUT / 64;  // half4 chunks per lane per edge
  constexpr int NE = NQ * 4;     // fp32 acc elements per lane
  int wid = (int)((blockIdx.x * blockDim.x + threadIdx.x) >> 6);
  int lane = threadIdx.x & 63;
  int grp = lane >> 4;
  int sl = lane & 15;
  if (wid >= M) return;

  // per-lane columns: q*64 + sl*4 + [0,4)
  half2v xr2[NQ * 2], att2[NQ * 2];
  {
    const half4* xrp =
        reinterpret_cast<const half4*>(xr) + (size_t)wid * (DOUT / 4) + sl;
#pragma unroll
    for (int q = 0; q < NQ; ++q) {
      half4 r4 = xrp[q * 16];
      half2v lo, hi;
      lo[0] = r4[0]; lo[1] = r4[1];
      hi[0] = r4[2]; hi[1] = r4[3];
      xr2[q * 2] = lo;
      xr2[q * 2 + 1] = hi;
    }
#pragma unroll
    for (int q = 0; q < NQ; ++q) {
#pragma unroll
      for (int t = 0; t < 2; ++t) {
        int c = q * 64 + sl * 4 + t * 2;
        half2v a2;
        a2[0] = (_Float16)att[c];
        a2[1] = (_Float16)att[c + 1];
        att2[q * 2 + t] = a2;
      }
    }
  }
  half2v v02;
  v02[0] = (_Float16)0.2f;
  v02[1] = (_Float16)0.2f;

  float acc[NE];
#pragma unroll
  for (int i = 0; i < NE; ++i) acc[i] = 0.f;
  float m = NEG_BIG, s = 0.f;
  int e0 = row_ptr[wid], e1 = row_ptr[wid + 1];
  int j = e0 + grp;  // this group's edge stream: j, j+4, j+8, ...

  const half4* base = reinterpret_cast<const half4*>(xl);
  half4 Axv[NQ], Bxv[NQ], Cxv[NQ];
  {
    int iA = (j < e1) ? col_src[j] : 0;
    int iB = (j + 4 < e1) ? col_src[j + 4] : 0;
    int iC = (j + 8 < e1) ? col_src[j + 8] : 0;
    const half4* rpA = base + (size_t)iA * (DOUT / 4) + sl;
    const half4* rpB = base + (size_t)iB * (DOUT / 4) + sl;
    const half4* rpC = base + (size_t)iC * (DOUT / 4) + sl;
#pragma unroll
    for (int q = 0; q < NQ; ++q) Axv[q] = rpA[q * 16];
#pragma unroll
    for (int q = 0; q < NQ; ++q) Bxv[q] = rpB[q * 16];
#pragma unroll
    for (int q = 0; q < NQ; ++q) Cxv[q] = rpC[q * 16];
  }

  while (j < e1) {
    PROC3(Axv);
    j += 4;
    if (j >= e1) break;
    PROC3(Bxv);
    j += 4;
    if (j >= e1) break;
    PROC3(Cxv);
    j += 4;
  }

  // merge (m, s) across the 4 groups (m is each group's reference point)
  float mg = m;
  float mm = m, ss = s;
#pragma unroll
  for (int off = 16; off < 64; off <<= 1) {
    float mo = __shfl_xor(mm, off, 64);
    float so = __shfl_xor(ss, off, 64);
    float nm = fmaxf(mm, mo);
    ss = ss * __expf(mm - nm) + so * __expf(mo - nm);
    mm = nm;
  }
  float scale = __expf(mg - mm) / ss;  // ss > 0 (deg >= 1 via self-loop)
#pragma unroll
  for (int i = 0; i < NE; ++i) {
    float v = acc[i] * scale;
#pragma unroll
    for (int off = 16; off < 64; off <<= 1) v += __shfl_xor(v, off, 64);
    acc[i] = v;
  }
  // chunk q written by group (q & 3); fp16 output (half4 = 8B store)
#pragma unroll
  for (int q = 0; q < NQ; ++q) {
    if (grp == (q & 3)) {
      int c = q * 64 + sl * 4;
      float4 b4 = *reinterpret_cast<const float4*>(bias + c);
      float o0 = acc[q * 4 + 0] + b4.x;
      float o1 = acc[q * 4 + 1] + b4.y;
      float o2 = acc[q * 4 + 2] + b4.z;
      float o3 = acc[q * 4 + 3] + b4.w;
      if (RELU) {
        o0 = fmaxf(o0, 0.f); o1 = fmaxf(o1, 0.f);
        o2 = fmaxf(o2, 0.f); o3 = fmaxf(o3, 0.f);
      }
      half4 oh;
      oh[0] = (_Float16)o0; oh[1] = (_Float16)o1;
      oh[2] = (_Float16)o2; oh[3] = (_Float16)o3;
      *reinterpret_cast<half4*>(out + (size_t)wid * DOUT + c) = oh;
    }
  }
}

extern "C" void kernel_launch(void* const* d_in, const int* in_sizes, int n_in,
                              void* d_out, int out_size, void* d_ws,
                              size_t ws_size, hipStream_t stream) {
  const float* x = (const float*)d_in[0];
  const int* ei = (const int*)d_in[1];
  const float* w1l = (const float*)d_in[2];
  const float* b1l = (const float*)d_in[3];
  const float* w1r = (const float*)d_in[4];
  const float* b1r = (const float*)d_in[5];
  const float* a1 = (const float*)d_in[6];
  const float* o1 = (const float*)d_in[7];
  const float* w2l = (const float*)d_in[8];
  const float* b2l = (const float*)d_in[9];
  const float* w2r = (const float*)d_in[10];
  const float* b2r = (const float*)d_in[11];
  const float* a2 = (const float*)d_in[12];
  const float* o2 = (const float*)d_in[13];
  const float* w3l = (const float*)d_in[14];
  const float* b3l = (const float*)d_in[15];
  const float* w3r = (const float*)d_in[16];
  const float* b3r = (const float*)d_in[17];
  const float* a3 = (const float*)d_in[18];
  const float* o3 = (const float*)d_in[19];
  const float* wc = (const float*)d_in[20];
  const float* bc = (const float*)d_in[21];
  float* out = (float*)d_out;

  const int n = in_sizes[0] / 128;  // 50000
  const int E = in_sizes[1] / 2;    // 800000
  const int tot = E + n;
  const int nchunks = (n + 1023) / 1024;  // <= 64 required

  // workspace layout
  char* p = (char*)d_ws;
  int* row_ptr = (int*)p; p += (size_t)(n + 1) * 4;
  int* deg = (int*)p;     p += (size_t)n * 4;
  int* cursor = (int*)p;  p += (size_t)n * 4;
  int* partial = (int*)p; p += (size_t)64 * 4;
  int* col_src = (int*)p; p += (size_t)tot * 4;
  p = (char*)(((uintptr_t)p + 255) & ~(uintptr_t)255);
  // packed weights: layers 1,2: 16384 elems; layer 3: 32768; wc: 12288
  const size_t SZ12 = 16384, SZ3 = 32768, SZC = 12288;
  ushort_t* pk[14];
  for (int i = 0; i < 8; ++i) { pk[i] = (ushort_t*)p; p += SZ12 * 2; }
  for (int i = 8; i < 12; ++i) { pk[i] = (ushort_t*)p; p += SZ3 * 2; }
  for (int i = 12; i < 14; ++i) { pk[i] = (ushort_t*)p; p += SZC * 2; }
  p = (char*)(((uintptr_t)p + 255) & ~(uintptr_t)255);
  _Float16* bufA = (_Float16*)p; p += (size_t)n * 256 * 2;  // h (fp16)
  _Float16* bufL = (_Float16*)p; p += (size_t)n * 256 * 2;  // xl (fp16)
  _Float16* bufR = (_Float16*)p;                            // xr (fp16)

  const int TPB = 256;

  // CSR build
  zero_int_kernel<<<(n + TPB - 1) / TPB, TPB, 0, stream>>>(deg, n);
  deg_count_kernel<<<(tot + TPB - 1) / TPB, TPB, 0, stream>>>(ei + E, E, n, deg);
  block_sum_kernel<<<nchunks, 256, 0, stream>>>(deg, n, partial);
  scan_partial_kernel<<<1, 64, 0, stream>>>(partial, nchunks);
  block_scan_kernel<<<nchunks, 1024, 0, stream>>>(deg, partial, row_ptr, cursor, n);
  scatter_kernel<<<(tot + TPB - 1) / TPB, TPB, 0, stream>>>(ei, ei + E, E, n,
                                                            cursor, col_src);

  // pack 6 weight matrices + classifier into MFMA B-fragment hi/lo arrays
  PackArgs pa;
  pa.w[0] = w1l; pa.w[1] = w1r; pa.w[2] = w2l; pa.w[3] = w2r;
  pa.w[4] = w3l; pa.w[5] = w3r; pa.w[6] = wc;
  pa.hi[0] = pk[0]; pa.lo[0] = pk[1];
  pa.hi[1] = pk[2]; pa.lo[1] = pk[3];
  pa.hi[2] = pk[4]; pa.lo[2] = pk[5];
  pa.hi[3] = pk[6]; pa.lo[3] = pk[7];
  pa.hi[4] = pk[8]; pa.lo[4] = pk[9];
  pa.hi[5] = pk[10]; pa.lo[5] = pk[11];
  pa.hi[6] = pk[12]; pa.lo[6] = pk[13];
  pa.ntiles[0] = pa.ntiles[1] = pa.ntiles[2] = pa.ntiles[3] = 8;
  pa.ntiles[4] = pa.ntiles[5] = 16;
  pa.ntiles[6] = 3;
  pa.kslices[0] = pa.kslices[1] = pa.kslices[2] = pa.kslices[3] = 4;
  pa.kslices[4] = pa.kslices[5] = 4;
  pa.kslices[6] = 8;
  pa.N[0] = pa.N[1] = pa.N[2] = pa.N[3] = 128;
  pa.N[4] = pa.N[5] = 256;
  pa.N[6] = 40;
  pack_w_kernel<<<dim3(128, 7), 256, 0, stream>>>(pa);

  const int gemmGrid = (n + 63) / 64;
  const int waveGrid = (n + 3) / 4;

  // Layer 1 (128 -> 128) + ReLU   (fp32 input x)
  gemm_dual_mfma<float><<<dim3(gemmGrid, 1), TPB, 0, stream>>>(
      x, pk[0], pk[1], pk[2], pk[3], b1l, b1r, bufL, bufR, n, 128, 8);
  attn_kernel<128, true><<<waveGrid, TPB, 0, stream>>>(bufL, bufR, a1, o1,
                                                       row_ptr, col_src, bufA, n);
  // Layer 2 (128 -> 128) + ReLU   (fp16 input h)
  gemm_dual_mfma<_Float16><<<dim3(gemmGrid, 1), TPB, 0, stream>>>(
      bufA, pk[4], pk[5], pk[6], pk[7], b2l, b2r, bufL, bufR, n, 128, 8);
  attn_kernel<128, true><<<waveGrid, TPB, 0, stream>>>(bufL, bufR, a2, o2,
                                                       row_ptr, col_src, bufA, n);
  // Layer 3 (128 -> 256), no ReLU (fp16 input h)
  gemm_dual_mfma<_Float16><<<dim3(gemmGrid, 2), TPB, 0, stream>>>(
      bufA, pk[8], pk[9], pk[10], pk[11], b3l, b3r, bufL, bufR, n, 256, 16);
  attn_kernel<256, false><<<waveGrid, TPB, 0, stream>>>(bufL, bufR, a3, o3,
                                                        row_ptr, col_src, bufA, n);
  // Classifier (256 -> 40) via MFMA (fp16 input h)
  classifier_mfma<<<gemmGrid, TPB, 0, stream>>>(bufA, pk[12], pk[13], bc, out, n);
}

// Round 10
// 405.507 us; speedup vs baseline: 1.3314x; 1.0039x over previous
//
#include <hip/hip_runtime.h>
#include <math.h>
#include <stdint.h>

// ---------------------------------------------------------------------------
// GATv2 3-layer network on MI355X.
//   1) CSR build by dst (deg count -> 3-kernel scan -> scatter).
//   2) Weights (6 layer mats + classifier) pre-packed into MFMA B-fragment
//      order as bf16 hi/lo pairs (classifier zero-padded 40 -> 48 cols).
//   3) Per layer: ONE fused MFMA kernel computes xl=h@Wl+bl and xr=h@Wr+br,
//      both emitted fp16, via split-bf16. Hidden state h fp16 end-to-end.
//      Attention: one wave per dst node, 4x 16-lane edge groups; 3-buffer
//      UNROLLED rotation with ONE-PROC-AHEAD index staging (r9 lesson: index
//      load in the same body as its gather = serial L2 chain; stage it one
//      PROC early so the refill gather issues with a ready index).
//      Packed-fp16 score, defer-max (THR=8), fp32 aggregation, fp16 out.
//   4) Classifier via MFMA (fp16 input).
// ---------------------------------------------------------------------------

typedef __attribute__((ext_vector_type(8))) short bf16x8;
typedef __attribute__((ext_vector_type(4))) float f32x4;
typedef __attribute__((ext_vector_type(4))) _Float16 half4;
typedef __attribute__((ext_vector_type(8))) _Float16 half8;
typedef __attribute__((ext_vector_type(2))) _Float16 half2v;
typedef unsigned short ushort_t;

__device__ inline ushort_t bf16_rne(float f) {
  unsigned u = __float_as_uint(f);
  unsigned r = (u + 0x7FFFu + ((u >> 16) & 1u)) >> 16;
  return (ushort_t)r;
}
__device__ inline float bf16_to_f(ushort_t h) {
  return __uint_as_float(((unsigned)h) << 16);
}

__device__ inline float fdot2f(half2v a, half2v b, float c) {
#if __has_builtin(__builtin_amdgcn_fdot2)
  return __builtin_amdgcn_fdot2(a, b, c, false);
#else
  return c + (float)a[0] * (float)b[0] + (float)a[1] * (float)b[1];
#endif
}
__device__ inline half2v h2max(half2v a, half2v b) {
#if __has_builtin(__builtin_elementwise_max)
  return __builtin_elementwise_max(a, b);
#else
  half2v r;
  r[0] = a[0] > b[0] ? a[0] : b[0];
  r[1] = a[1] > b[1] ? a[1] : b[1];
  return r;
#endif
}

__global__ void zero_int_kernel(int* __restrict__ p, int n) {
  int i = blockIdx.x * blockDim.x + threadIdx.x;
  if (i < n) p[i] = 0;
}

__global__ void deg_count_kernel(const int* __restrict__ dst, int E, int n,
                                 int* __restrict__ deg) {
  int i = blockIdx.x * blockDim.x + threadIdx.x;
  int tot = E + n;
  if (i < tot) {
    int d = (i < E) ? dst[i] : (i - E);
    atomicAdd(&deg[d], 1);
  }
}

// 3-phase exclusive scan over deg[n], chunk=1024. nchunks must be <= 64.
__global__ __launch_bounds__(256) void block_sum_kernel(
    const int* __restrict__ deg, int n, int* __restrict__ partial) {
  __shared__ int sm[256];
  int base = blockIdx.x * 1024;
  int t = threadIdx.x;
  int sum = 0;
#pragma unroll
  for (int k = 0; k < 4; ++k) {
    int i = base + k * 256 + t;
    sum += (i < n) ? deg[i] : 0;
  }
  sm[t] = sum;
  __syncthreads();
  for (int off = 128; off > 0; off >>= 1) {
    if (t < off) sm[t] += sm[t + off];
    __syncthreads();
  }
  if (t == 0) partial[blockIdx.x] = sm[0];
}

__global__ void scan_partial_kernel(int* __restrict__ partial, int nchunks) {
  int lane = threadIdx.x;  // 64 threads
  int v = (lane < nchunks) ? partial[lane] : 0;
#pragma unroll
  for (int off = 1; off < 64; off <<= 1) {
    int u = __shfl_up(v, off, 64);
    if (lane >= off) v += u;
  }
  int ex = __shfl_up(v, 1, 64);
  if (lane == 0) ex = 0;
  if (lane < nchunks) partial[lane] = ex;
}

__global__ __launch_bounds__(1024) void block_scan_kernel(
    const int* __restrict__ deg, const int* __restrict__ partial,
    int* __restrict__ row_ptr, int* __restrict__ cursor, int n) {
  __shared__ int sm[1024];
  int i = blockIdx.x * 1024 + threadIdx.x;
  int v = (i < n) ? deg[i] : 0;
  sm[threadIdx.x] = v;
  __syncthreads();
  for (int off = 1; off < 1024; off <<= 1) {
    int t = (threadIdx.x >= off) ? sm[threadIdx.x - off] : 0;
    __syncthreads();
    sm[threadIdx.x] += t;
    __syncthreads();
  }
  int excl = partial[blockIdx.x] + sm[threadIdx.x] - v;
  if (i < n) {
    row_ptr[i] = excl;
    cursor[i] = excl;
  }
  if (i == n - 1) row_ptr[n] = excl + v;
}

__global__ void scatter_kernel(const int* __restrict__ src,
                               const int* __restrict__ dst, int E, int n,
                               int* __restrict__ cursor,
                               int* __restrict__ col_src) {
  int i = blockIdx.x * blockDim.x + threadIdx.x;
  int tot = E + n;
  if (i < tot) {
    int s = (i < E) ? src[i] : (i - E);
    int d = (i < E) ? dst[i] : (i - E);
    int slot = atomicAdd(&cursor[d], 1);
    col_src[slot] = s;
  }
}

// --------------------------- weight packing --------------------------------
// Fragment order for mfma_f32_16x16x32_bf16 B operand:
//   idx = ((ks*ntiles + t)*64 + lane)*8 + i -> W[ks*32+8*(lane>>4)+i][16t+(lane&15)]
// Zero-pads columns c >= N (classifier: 40 cols padded to 3 tiles = 48).
struct PackArgs {
  const float* w[7];
  ushort_t* hi[7];
  ushort_t* lo[7];
  int ntiles[7];
  int kslices[7];
  int N[7];
};

__global__ __launch_bounds__(256) void pack_w_kernel(PackArgs a) {
  int m = blockIdx.y;
  int ntiles = a.ntiles[m];
  int N = a.N[m];
  int tot = a.kslices[m] * ntiles * 512;
  int idx = blockIdx.x * 256 + threadIdx.x;
  if (idx >= tot) return;
  int i = idx & 7;
  int lane = (idx >> 3) & 63;
  int t = (idx >> 9) % ntiles;
  int ks = idx / (512 * ntiles);
  int k = ks * 32 + (lane >> 4) * 8 + i;
  int c = t * 16 + (lane & 15);
  float f = (c < N) ? a.w[m][k * N + c] : 0.f;
  ushort_t h = bf16_rne(f);
  a.hi[m][idx] = h;
  a.lo[m][idx] = bf16_rne(f - bf16_to_f(h));
}

// ----------------------- fused dual MFMA GEMM ------------------------------
// Yl (fp16) = X@Wl+Bl, Yr (fp16) = X@Wr+Br.  X: [M][128] fp32 OR fp16.
// Block: 256 thr = 4 waves; wave handles 16 rows x 128 cols (8 16x16 tiles).
// grid.y selects a 128-col panel (for N=256).
template <typename TIN>
__global__ __launch_bounds__(256) void gemm_dual_mfma(
    const TIN* __restrict__ X, const ushort_t* __restrict__ wlhi,
    const ushort_t* __restrict__ wllo, const ushort_t* __restrict__ wrhi,
    const ushort_t* __restrict__ wrlo, const float* __restrict__ Bl,
    const float* __restrict__ Br, _Float16* __restrict__ Yl,
    _Float16* __restrict__ Yr, int M, int N, int ntot) {
  int lane = threadIdx.x & 63;
  int wv = threadIdx.x >> 6;
  int kg = lane >> 4;  // 0..3
  int li = lane & 15;
  int rbase = blockIdx.x * 64 + wv * 16;
  int colofs = blockIdx.y * 128;
  int tbase = colofs >> 4;
  int arow = rbase + li;
  int ar = (arow < M) ? arow : (M - 1);
  const TIN* xp = X + (size_t)ar * 128 + kg * 8;

  f32x4 accl[8], accr[8];
#pragma unroll
  for (int t = 0; t < 8; ++t) {
    accl[t] = (f32x4){0.f, 0.f, 0.f, 0.f};
    accr[t] = (f32x4){0.f, 0.f, 0.f, 0.f};
  }

#pragma unroll
  for (int ks = 0; ks < 4; ++ks) {
    float av[8];
    if constexpr (sizeof(TIN) == 4) {
      float4 a0 = *reinterpret_cast<const float4*>(xp + ks * 32);
      float4 a1 = *reinterpret_cast<const float4*>(xp + ks * 32 + 4);
      av[0] = a0.x; av[1] = a0.y; av[2] = a0.z; av[3] = a0.w;
      av[4] = a1.x; av[5] = a1.y; av[6] = a1.z; av[7] = a1.w;
    } else {
      half8 h8 = *reinterpret_cast<const half8*>(xp + ks * 32);
#pragma unroll
      for (int i = 0; i < 8; ++i) av[i] = (float)h8[i];
    }
    bf16x8 ah, al;
#pragma unroll
    for (int i = 0; i < 8; ++i) {
      ushort_t h = bf16_rne(av[i]);
      ah[i] = (short)h;
      al[i] = (short)bf16_rne(av[i] - bf16_to_f(h));
    }
    size_t fb = ((size_t)ks * ntot + tbase) * 512 + (size_t)lane * 8;
#pragma unroll
    for (int t = 0; t < 8; ++t) {
      size_t o = fb + (size_t)t * 512;
      bf16x8 blh = *reinterpret_cast<const bf16x8*>(wlhi + o);
      bf16x8 bll = *reinterpret_cast<const bf16x8*>(wllo + o);
      bf16x8 brh = *reinterpret_cast<const bf16x8*>(wrhi + o);
      bf16x8 brl = *reinterpret_cast<const bf16x8*>(wrlo + o);
      accl[t] = __builtin_amdgcn_mfma_f32_16x16x32_bf16(ah, blh, accl[t], 0, 0, 0);
      accl[t] = __builtin_amdgcn_mfma_f32_16x16x32_bf16(ah, bll, accl[t], 0, 0, 0);
      accl[t] = __builtin_amdgcn_mfma_f32_16x16x32_bf16(al, blh, accl[t], 0, 0, 0);
      accr[t] = __builtin_amdgcn_mfma_f32_16x16x32_bf16(ah, brh, accr[t], 0, 0, 0);
      accr[t] = __builtin_amdgcn_mfma_f32_16x16x32_bf16(ah, brl, accr[t], 0, 0, 0);
      accr[t] = __builtin_amdgcn_mfma_f32_16x16x32_bf16(al, brh, accr[t], 0, 0, 0);
    }
  }
  // D layout: row = 4*(lane>>4)+reg, col = 16t + (lane&15)
  int srow = rbase + kg * 4;
#pragma unroll
  for (int t = 0; t < 8; ++t) {
    int col = colofs + t * 16 + li;
    float bl = Bl[col];
    float br = Br[col];
#pragma unroll
    for (int r = 0; r < 4; ++r) {
      int rr = srow + r;
      if (rr < M) {
        Yl[(size_t)rr * N + col] = (_Float16)(accl[t][r] + bl);
        Yr[(size_t)rr * N + col] = (_Float16)(accr[t][r] + br);
      }
    }
  }
}

// ----------------------- classifier via MFMA -------------------------------
// out[M][40] = H[M][256] @ WC[256][40] + BC.  H fp16. WC packed to 3 tiles.
__global__ __launch_bounds__(256) void classifier_mfma(
    const _Float16* __restrict__ H, const ushort_t* __restrict__ wchi,
    const ushort_t* __restrict__ wclo, const float* __restrict__ BC,
    float* __restrict__ out, int M) {
  int lane = threadIdx.x & 63;
  int wv = threadIdx.x >> 6;
  int kg = lane >> 4;
  int li = lane & 15;
  int rbase = blockIdx.x * 64 + wv * 16;
  int arow = rbase + li;
  int ar = (arow < M) ? arow : (M - 1);
  const _Float16* xp = H + (size_t)ar * 256 + kg * 8;

  f32x4 acc[3];
#pragma unroll
  for (int t = 0; t < 3; ++t) acc[t] = (f32x4){0.f, 0.f, 0.f, 0.f};

#pragma unroll
  for (int ks = 0; ks < 8; ++ks) {
    half8 h8 = *reinterpret_cast<const half8*>(xp + ks * 32);
    bf16x8 ah, al;
#pragma unroll
    for (int i = 0; i < 8; ++i) {
      float f = (float)h8[i];
      ushort_t h = bf16_rne(f);
      ah[i] = (short)h;
      al[i] = (short)bf16_rne(f - bf16_to_f(h));
    }
    size_t fb = ((size_t)ks * 3) * 512 + (size_t)lane * 8;
#pragma unroll
    for (int t = 0; t < 3; ++t) {
      size_t o = fb + (size_t)t * 512;
      bf16x8 bh = *reinterpret_cast<const bf16x8*>(wchi + o);
      bf16x8 bl = *reinterpret_cast<const bf16x8*>(wclo + o);
      acc[t] = __builtin_amdgcn_mfma_f32_16x16x32_bf16(ah, bh, acc[t], 0, 0, 0);
      acc[t] = __builtin_amdgcn_mfma_f32_16x16x32_bf16(ah, bl, acc[t], 0, 0, 0);
      acc[t] = __builtin_amdgcn_mfma_f32_16x16x32_bf16(al, bh, acc[t], 0, 0, 0);
    }
  }
  int srow = rbase + kg * 4;
#pragma unroll
  for (int t = 0; t < 3; ++t) {
    int col = t * 16 + li;
    if (col < 40) {
      float b = BC[col];
#pragma unroll
      for (int r = 0; r < 4; ++r) {
        int rr = srow + r;
        if (rr < M) out[(size_t)rr * 40 + col] = acc[t][r] + b;
      }
    }
  }
}

// --------------------------- attention -------------------------------------
// One wave per dst node; 4x 16-lane groups, each with its own online-softmax
// over a strided slice of the edge list. 3-buffer unrolled rotation with
// one-PROC-ahead index staging: `inext` holds col_src[j+12] on entry; the
// body first issues the load of col_src[j+16], computes the score (consuming
// X), then refills X for j+12 with the READY index. Packed fp16 score,
// defer-max (THR=8), fp32 aggregation, fp16 output.
#define NEG_BIG (-1e30f)

#define PROC3(X)                                                          \
  {                                                                       \
    int iuse = inext;                                                     \
    inext = (j + 16 < e1) ? col_src[j + 16] : 0;                          \
    float p = 0.f;                                                        \
    float xf[NE];                                                         \
    _Pragma("unroll") for (int q = 0; q < NQ; ++q) {                      \
      _Pragma("unroll") for (int t = 0; t < 2; ++t) {                     \
        half2v xa;                                                        \
        xa[0] = X[q][2 * t];                                              \
        xa[1] = X[q][2 * t + 1];                                          \
        half2v tt = xa + xr2[q * 2 + t];                                  \
        tt = h2max(tt, tt * v02);                                         \
        p = fdot2f(tt, att2[q * 2 + t], p);                               \
        xf[q * 4 + 2 * t] = (float)xa[0];                                 \
        xf[q * 4 + 2 * t + 1] = (float)xa[1];                             \
      }                                                                   \
    }                                                                     \
    {                                                                     \
      const half4* rp = base + (size_t)iuse * (DOUT / 4) + sl;            \
      _Pragma("unroll") for (int q = 0; q < NQ; ++q) X[q] = rp[q * 16];   \
    }                                                                     \
    _Pragma("unroll") for (int off = 1; off < 16; off <<= 1)              \
        p += __shfl_xor(p, off, 64);                                      \
    if (p > m + 8.0f) {                                                   \
      float sc = __expf(m - p);                                           \
      s = s * sc + 1.f;                                                   \
      _Pragma("unroll") for (int i = 0; i < NE; ++i)                      \
          acc[i] = fmaf(acc[i], sc, xf[i]);                               \
      m = p;                                                              \
    } else {                                                              \
      float pe = __expf(p - m);                                           \
      s += pe;                                                            \
      _Pragma("unroll") for (int i = 0; i < NE; ++i)                      \
          acc[i] = fmaf(pe, xf[i], acc[i]);                               \
    }                                                                     \
  }

template <int DOUT, bool RELU>
__global__ __launch_bounds__(256) void attn_kernel(
    const _Float16* __restrict__ xl, const _Float16* __restrict__ xr,
    const float* __restrict__ att, const float* __restrict__ bias,
    const int* __restrict__ row_ptr, const int* __restrict__ col_src,
    _Float16* __restrict__ out, int M) {
  constexpr int NQ = DOUT / 64;  // half4 chunks per lane per edge
  constexpr int NE = NQ * 4;     // fp32 acc elements per lane
  int wid = (int)((blockIdx.x * blockDim.x + threadIdx.x) >> 6);
  int lane = threadIdx.x & 63;
  int grp = lane >> 4;
  int sl = lane & 15;
  if (wid >= M) return;

  // per-lane columns: q*64 + sl*4 + [0,4)
  half2v xr2[NQ * 2], att2[NQ * 2];
  {
    const half4* xrp =
        reinterpret_cast<const half4*>(xr) + (size_t)wid * (DOUT / 4) + sl;
#pragma unroll
    for (int q = 0; q < NQ; ++q) {
      half4 r4 = xrp[q * 16];
      half2v lo, hi;
      lo[0] = r4[0]; lo[1] = r4[1];
      hi[0] = r4[2]; hi[1] = r4[3];
      xr2[q * 2] = lo;
      xr2[q * 2 + 1] = hi;
    }
#pragma unroll
    for (int q = 0; q < NQ; ++q) {
#pragma unroll
      for (int t = 0; t < 2; ++t) {
        int c = q * 64 + sl * 4 + t * 2;
        half2v a2;
        a2[0] = (_Float16)att[c];
        a2[1] = (_Float16)att[c + 1];
        att2[q * 2 + t] = a2;
      }
    }
  }
  half2v v02;
  v02[0] = (_Float16)0.2f;
  v02[1] = (_Float16)0.2f;

  float acc[NE];
#pragma unroll
  for (int i = 0; i < NE; ++i) acc[i] = 0.f;
  float m = NEG_BIG, s = 0.f;
  int e0 = row_ptr[wid], e1 = row_ptr[wid + 1];
  int j = e0 + grp;  // this group's edge stream: j, j+4, j+8, ...

  const half4* base = reinterpret_cast<const half4*>(xl);
  half4 Axv[NQ], Bxv[NQ], Cxv[NQ];
  int inext;
  {
    int iA = (j < e1) ? col_src[j] : 0;
    int iB = (j + 4 < e1) ? col_src[j + 4] : 0;
    int iC = (j + 8 < e1) ? col_src[j + 8] : 0;
    inext = (j + 12 < e1) ? col_src[j + 12] : 0;
    const half4* rpA = base + (size_t)iA * (DOUT / 4) + sl;
    const half4* rpB = base + (size_t)iB * (DOUT / 4) + sl;
    const half4* rpC = base + (size_t)iC * (DOUT / 4) + sl;
#pragma unroll
    for (int q = 0; q < NQ; ++q) Axv[q] = rpA[q * 16];
#pragma unroll
    for (int q = 0; q < NQ; ++q) Bxv[q] = rpB[q * 16];
#pragma unroll
    for (int q = 0; q < NQ; ++q) Cxv[q] = rpC[q * 16];
  }

  while (j < e1) {
    PROC3(Axv);
    j += 4;
    if (j >= e1) break;
    PROC3(Bxv);
    j += 4;
    if (j >= e1) break;
    PROC3(Cxv);
    j += 4;
  }

  // merge (m, s) across the 4 groups (m is each group's reference point)
  float mg = m;
  float mm = m, ss = s;
#pragma unroll
  for (int off = 16; off < 64; off <<= 1) {
    float mo = __shfl_xor(mm, off, 64);
    float so = __shfl_xor(ss, off, 64);
    float nm = fmaxf(mm, mo);
    ss = ss * __expf(mm - nm) + so * __expf(mo - nm);
    mm = nm;
  }
  float scale = __expf(mg - mm) / ss;  // ss > 0 (deg >= 1 via self-loop)
#pragma unroll
  for (int i = 0; i < NE; ++i) {
    float v = acc[i] * scale;
#pragma unroll
    for (int off = 16; off < 64; off <<= 1) v += __shfl_xor(v, off, 64);
    acc[i] = v;
  }
  // chunk q written by group (q & 3); fp16 output (half4 = 8B store)
#pragma unroll
  for (int q = 0; q < NQ; ++q) {
    if (grp == (q & 3)) {
      int c = q * 64 + sl * 4;
      float4 b4 = *reinterpret_cast<const float4*>(bias + c);
      float o0 = acc[q * 4 + 0] + b4.x;
      float o1 = acc[q * 4 + 1] + b4.y;
      float o2 = acc[q * 4 + 2] + b4.z;
      float o3 = acc[q * 4 + 3] + b4.w;
      if (RELU) {
        o0 = fmaxf(o0, 0.f); o1 = fmaxf(o1, 0.f);
        o2 = fmaxf(o2, 0.f); o3 = fmaxf(o3, 0.f);
      }
      half4 oh;
      oh[0] = (_Float16)o0; oh[1] = (_Float16)o1;
      oh[2] = (_Float16)o2; oh[3] = (_Float16)o3;
      *reinterpret_cast<half4*>(out + (size_t)wid * DOUT + c) = oh;
    }
  }
}

extern "C" void kernel_launch(void* const* d_in, const int* in_sizes, int n_in,
                              void* d_out, int out_size, void* d_ws,
                              size_t ws_size, hipStream_t stream) {
  const float* x = (const float*)d_in[0];
  const int* ei = (const int*)d_in[1];
  const float* w1l = (const float*)d_in[2];
  const float* b1l = (const float*)d_in[3];
  const float* w1r = (const float*)d_in[4];
  const float* b1r = (const float*)d_in[5];
  const float* a1 = (const float*)d_in[6];
  const float* o1 = (const float*)d_in[7];
  const float* w2l = (const float*)d_in[8];
  const float* b2l = (const float*)d_in[9];
  const float* w2r = (const float*)d_in[10];
  const float* b2r = (const float*)d_in[11];
  const float* a2 = (const float*)d_in[12];
  const float* o2 = (const float*)d_in[13];
  const float* w3l = (const float*)d_in[14];
  const float* b3l = (const float*)d_in[15];
  const float* w3r = (const float*)d_in[16];
  const float* b3r = (const float*)d_in[17];
  const float* a3 = (const float*)d_in[18];
  const float* o3 = (const float*)d_in[19];
  const float* wc = (const float*)d_in[20];
  const float* bc = (const float*)d_in[21];
  float* out = (float*)d_out;

  const int n = in_sizes[0] / 128;  // 50000
  const int E = in_sizes[1] / 2;    // 800000
  const int tot = E + n;
  const int nchunks = (n + 1023) / 1024;  // <= 64 required

  // workspace layout
  char* p = (char*)d_ws;
  int* row_ptr = (int*)p; p += (size_t)(n + 1) * 4;
  int* deg = (int*)p;     p += (size_t)n * 4;
  int* cursor = (int*)p;  p += (size_t)n * 4;
  int* partial = (int*)p; p += (size_t)64 * 4;
  int* col_src = (int*)p; p += (size_t)tot * 4;
  p = (char*)(((uintptr_t)p + 255) & ~(uintptr_t)255);
  // packed weights: layers 1,2: 16384 elems; layer 3: 32768; wc: 12288
  const size_t SZ12 = 16384, SZ3 = 32768, SZC = 12288;
  ushort_t* pk[14];
  for (int i = 0; i < 8; ++i) { pk[i] = (ushort_t*)p; p += SZ12 * 2; }
  for (int i = 8; i < 12; ++i) { pk[i] = (ushort_t*)p; p += SZ3 * 2; }
  for (int i = 12; i < 14; ++i) { pk[i] = (ushort_t*)p; p += SZC * 2; }
  p = (char*)(((uintptr_t)p + 255) & ~(uintptr_t)255);
  _Float16* bufA = (_Float16*)p; p += (size_t)n * 256 * 2;  // h (fp16)
  _Float16* bufL = (_Float16*)p; p += (size_t)n * 256 * 2;  // xl (fp16)
  _Float16* bufR = (_Float16*)p;                            // xr (fp16)

  const int TPB = 256;

  // CSR build
  zero_int_kernel<<<(n + TPB - 1) / TPB, TPB, 0, stream>>>(deg, n);
  deg_count_kernel<<<(tot + TPB - 1) / TPB, TPB, 0, stream>>>(ei + E, E, n, deg);
  block_sum_kernel<<<nchunks, 256, 0, stream>>>(deg, n, partial);
  scan_partial_kernel<<<1, 64, 0, stream>>>(partial, nchunks);
  block_scan_kernel<<<nchunks, 1024, 0, stream>>>(deg, partial, row_ptr, cursor, n);
  scatter_kernel<<<(tot + TPB - 1) / TPB, TPB, 0, stream>>>(ei, ei + E, E, n,
                                                            cursor, col_src);

  // pack 6 weight matrices + classifier into MFMA B-fragment hi/lo arrays
  PackArgs pa;
  pa.w[0] = w1l; pa.w[1] = w1r; pa.w[2] = w2l; pa.w[3] = w2r;
  pa.w[4] = w3l; pa.w[5] = w3r; pa.w[6] = wc;
  pa.hi[0] = pk[0]; pa.lo[0] = pk[1];
  pa.hi[1] = pk[2]; pa.lo[1] = pk[3];
  pa.hi[2] = pk[4]; pa.lo[2] = pk[5];
  pa.hi[3] = pk[6]; pa.lo[3] = pk[7];
  pa.hi[4] = pk[8]; pa.lo[4] = pk[9];
  pa.hi[5] = pk[10]; pa.lo[5] = pk[11];
  pa.hi[6] = pk[12]; pa.lo[6] = pk[13];
  pa.ntiles[0] = pa.ntiles[1] = pa.ntiles[2] = pa.ntiles[3] = 8;
  pa.ntiles[4] = pa.ntiles[5] = 16;
  pa.ntiles[6] = 3;
  pa.kslices[0] = pa.kslices[1] = pa.kslices[2] = pa.kslices[3] = 4;
  pa.kslices[4] = pa.kslices[5] = 4;
  pa.kslices[6] = 8;
  pa.N[0] = pa.N[1] = pa.N[2] = pa.N[3] = 128;
  pa.N[4] = pa.N[5] = 256;
  pa.N[6] = 40;
  pack_w_kernel<<<dim3(128, 7), 256, 0, stream>>>(pa);

  const int gemmGrid = (n + 63) / 64;
  const int waveGrid = (n + 3) / 4;

  // Layer 1 (128 -> 128) + ReLU   (fp32 input x)
  gemm_dual_mfma<float><<<dim3(gemmGrid, 1), TPB, 0, stream>>>(
      x, pk[0], pk[1], pk[2], pk[3], b1l, b1r, bufL, bufR, n, 128, 8);
  attn_kernel<128, true><<<waveGrid, TPB, 0, stream>>>(bufL, bufR, a1, o1,
                                                       row_ptr, col_src, bufA, n);
  // Layer 2 (128 -> 128) + ReLU   (fp16 input h)
  gemm_dual_mfma<_Float16><<<dim3(gemmGrid, 1), TPB, 0, stream>>>(
      bufA, pk[4], pk[5], pk[6], pk[7], b2l, b2r, bufL, bufR, n, 128, 8);
  attn_kernel<128, true><<<waveGrid, TPB, 0, stream>>>(bufL, bufR, a2, o2,
                                                       row_ptr, col_src, bufA, n);
  // Layer 3 (128 -> 256), no ReLU (fp16 input h)
  gemm_dual_mfma<_Float16><<<dim3(gemmGrid, 2), TPB, 0, stream>>>(
      bufA, pk[8], pk[9], pk[10], pk[11], b3l, b3r, bufL, bufR, n, 256, 16);
  attn_kernel<256, false><<<waveGrid, TPB, 0, stream>>>(bufL, bufR, a3, o3,
                                                        row_ptr, col_src, bufA, n);
  // Classifier (256 -> 40) via MFMA (fp16 input h)
  classifier_mfma<<<gemmGrid, TPB, 0, stream>>>(bufA, pk[12], pk[13], bc, out, n);
}